// Round 12
// baseline (212.087 us; speedup 1.0000x reference)
//
#include <hip/hip_runtime.h>
#include <math.h>

#define HDIM  1024
#define HHALF 512
#define NEXP  8
#define NTOK  4096
#define CAP   1536
#define NTOT  2560                          // 512 + 1024 + 1024 concat output width
#define TOTAL_DC (2u * NTOK * NEXP * CAP)   // 100,663,296 floats (dispatch+combine)

typedef _Float16 f16x8 __attribute__((ext_vector_type(8)));
typedef float    f32x4 __attribute__((ext_vector_type(4)));

#define FILL_BLOCKS 1408
#define S_LO 2048.0f                        // lo-part scale (2^11)
#define S_W  32.0f                          // weight pre-scale

// ---------------------------------------------------------------------------
// prep: [0,2048) x -> A_hi/A_lo fp16 ; [2048,2688) weights -> Bt_hi/Bt_lo
// (transposed concat [2560][1024], pre-scaled x32) ; [2688] bias concat.
// ---------------------------------------------------------------------------
__global__ __launch_bounds__(256) void prep(
    const float* __restrict__ x,
    const float* __restrict__ wi1, const float* __restrict__ wr1,
    const float* __restrict__ wu1,
    const float* __restrict__ bi1, const float* __restrict__ br1,
    const float* __restrict__ bu1,
    _Float16* __restrict__ Ah, _Float16* __restrict__ Al,
    _Float16* __restrict__ Bth, _Float16* __restrict__ Btl,
    float* __restrict__ bias_cat)
{
    __shared__ float tile[64][65];
    const int bid = blockIdx.x, tid = threadIdx.x;

    if (bid < 2048) {                       // ---- x conversion, 8 elems/thread
        const int i8 = bid * 256 + tid;     // 0 .. 524287
        const float4* x4 = (const float4*)x;
        float4 v0 = x4[i8 * 2];
        float4 v1 = x4[i8 * 2 + 1];
        float f[8] = {v0.x, v0.y, v0.z, v0.w, v1.x, v1.y, v1.z, v1.w};
        f16x8 hi, lo;
#pragma unroll
        for (int j = 0; j < 8; j++) {
            _Float16 h = (_Float16)f[j];
            hi[j] = h;
            lo[j] = (_Float16)((f[j] - (float)h) * S_LO);
        }
        *(f16x8*)&Ah[(size_t)i8 * 8] = hi;
        *(f16x8*)&Al[(size_t)i8 * 8] = lo;
        return;
    }
    if (bid < 2688) {                       // ---- weight transpose+convert
        int local; const float* src; int C, nof;
        int b = bid - 2048;
        if (b < 128)      { src = wi1; C = 512;  nof = 0;    local = b; }
        else if (b < 384) { src = wr1; C = 1024; nof = 512;  local = b - 128; }
        else              { src = wu1; C = 1024; nof = 1536; local = b - 384; }
        const int nti = local >> 4, kti = local & 15;
#pragma unroll
        for (int p = 0; p < 16; p++) {
            int e = p * 256 + tid;
            int kr = e >> 6, nc = e & 63;
            tile[kr][nc] = src[(size_t)(kti * 64 + kr) * C + nti * 64 + nc];
        }
        __syncthreads();
#pragma unroll
        for (int p = 0; p < 16; p++) {
            int e = p * 256 + tid;
            int nl = e >> 6, kk = e & 63;
            float w32 = tile[kk][nl] * S_W;
            _Float16 h = (_Float16)w32;
            _Float16 l = (_Float16)((w32 - (float)h) * S_LO);
            const size_t o = (size_t)(nof + nti * 64 + nl) * 1024 + kti * 64 + kk;
            Bth[o] = h;
            Btl[o] = l;
        }
        return;
    }
    // ---- bias concat
    for (int i = tid; i < NTOT; i += 256) {
        float v = (i < 512) ? bi1[i] : (i < 1536) ? br1[i - 512] : bu1[i - 1536];
        bias_cat[i] = v;
    }
}

// ---------------------------------------------------------------------------
// gemm_fill: 2048 blocks in 256 octets of 8 (sub = blockIdx&7 = XCD).
// Octet groups of 8: first 11 groups = 7 GEMM + 1 fill octet; group 11 =
// 3 GEMM + 5 fill; groups 12..31 = all fill -> fill streams under GEMM phase.
// GEMM: fp16-split MFMA, 2-phase dbuf pipeline, XCD-sliced tiles, LDS swizzle.
// FUSED second-layer epilogue: relu(H-tile) . w2-slice -> per-(bn,half,token)
// partials (no H materialization).
// ---------------------------------------------------------------------------
__global__ __launch_bounds__(256, 2) void gemm_fill(
    const _Float16* __restrict__ Ah, const _Float16* __restrict__ Al,
    const _Float16* __restrict__ Bth, const _Float16* __restrict__ Btl,
    const float* __restrict__ bias_cat,
    const float* __restrict__ wi2, const float* __restrict__ wr2,
    const float* __restrict__ wu2,
    float* __restrict__ part, float* __restrict__ out)
{
    const int o = blockIdx.x >> 3, sub = blockIdx.x & 7;
    const int k = o >> 3, j = o & 7;        // octet group, position
    int g = -1, fo = 0;
    if (k < 11)       { if (j < 7) g = k * 7 + j; else fo = k; }
    else if (k == 11) { if (j < 3) g = 77 + j;    else fo = 11 + (j - 3); }
    else              { fo = 16 + ((k - 12) << 3) + j; }

    if (g < 0) {                            // ---------- fill path
        f32x4* o4 = (f32x4*)out;
        const unsigned total4 = TOTAL_DC / 4;            // 25,165,824
        unsigned i = (unsigned)(fo * 8 + sub) * 256u + threadIdx.x;
        const unsigned stride = FILL_BLOCKS * 256u;
        const f32x4 z = {0.f, 0.f, 0.f, 0.f};
        for (; i < total4; i += stride)
            __builtin_nontemporal_store(z, o4 + i);
        return;
    }

    __shared__ _Float16 lds[2][4][128][32];   // dbuf x {Ah|Al|Bh|Bl}, 64 KB

    const int tid = threadIdx.x;
    const int lane = tid & 63, wid = tid >> 6;

    // XCD-sliced mapping: xcd = sub; each XCD owns a bm-slice of 4, iterates
    // bm fastest so B panels are burst-reused.
    const int bm  = sub * 4 + (g & 3);        // 0..31
    const int bn  = g >> 2;                   // 0..19
    const int rowBase = bm * 128, colBase = bn * 128;

    // each wave stages its own tile type
    const _Float16* gb =
        (wid == 0) ? Ah  + (size_t)rowBase * 1024 :
        (wid == 1) ? Al  + (size_t)rowBase * 1024 :
        (wid == 2) ? Bth + (size_t)colBase * 1024 :
                     Btl + (size_t)colBase * 1024;
    const int lrow = lane >> 2;             // 0..15 within 16-row group
    // pre-swizzled 16B chunk within the 64B row (kept from R11, neutral/safe)
    const int lkgs = (lane & 3) ^ ((lane >> 3) & 3);

    f32x4 acc_hh[4][4], acc_x[4][4];
    const f32x4 z4 = {0.f, 0.f, 0.f, 0.f};
#pragma unroll
    for (int i = 0; i < 4; i++)
#pragma unroll
        for (int j2 = 0; j2 < 4; j2++) { acc_hh[i][j2] = z4; acc_x[i][j2] = z4; }

    const int mw = (wid >> 1) * 64, nw = (wid & 1) * 64;
    const int fr = lane & 15, s = lane >> 4;
    const int rs = s ^ ((fr >> 1) & 3);     // swizzled read chunk

#define STAGE(buf, k0)                                                        \
    {                                                                         \
        _Pragma("unroll")                                                     \
        for (int i = 0; i < 8; i++) {                                         \
            const int r = i * 16 + lrow;                                      \
            __builtin_amdgcn_global_load_lds(                                 \
                (const void*)(gb + (size_t)r * 1024 + (k0) + lkgs * 8),       \
                (void*)&lds[buf][wid][i * 16][0], 16, 0, 0);                  \
        }                                                                     \
    }

#define COMPUTE(buf)                                                          \
    {                                                                         \
        f16x8 fa_h[4], fa_l[4], fb_h[4], fb_l[4];                             \
        _Pragma("unroll")                                                     \
        for (int mf = 0; mf < 4; mf++) {                                      \
            fa_h[mf] = *(const f16x8*)&lds[buf][0][mw + mf * 16 + fr][rs * 8];\
            fa_l[mf] = *(const f16x8*)&lds[buf][1][mw + mf * 16 + fr][rs * 8];\
        }                                                                     \
        _Pragma("unroll")                                                     \
        for (int nf = 0; nf < 4; nf++) {                                      \
            fb_h[nf] = *(const f16x8*)&lds[buf][2][nw + nf * 16 + fr][rs * 8];\
            fb_l[nf] = *(const f16x8*)&lds[buf][3][nw + nf * 16 + fr][rs * 8];\
        }                                                                     \
        _Pragma("unroll")                                                     \
        for (int mf = 0; mf < 4; mf++)                                        \
            _Pragma("unroll")                                                 \
            for (int nf = 0; nf < 4; nf++) {                                  \
                acc_hh[mf][nf] = __builtin_amdgcn_mfma_f32_16x16x32_f16(      \
                    fa_h[mf], fb_h[nf], acc_hh[mf][nf], 0, 0, 0);             \
                acc_x[mf][nf] = __builtin_amdgcn_mfma_f32_16x16x32_f16(       \
                    fa_h[mf], fb_l[nf], acc_x[mf][nf], 0, 0, 0);              \
                acc_x[mf][nf] = __builtin_amdgcn_mfma_f32_16x16x32_f16(       \
                    fa_l[mf], fb_h[nf], acc_x[mf][nf], 0, 0, 0);              \
            }                                                                 \
    }

    STAGE(0, 0);
    __syncthreads();                        // buf0 staged

    for (int t = 0; t < 32; t += 2) {
        if (t + 1 < 32) STAGE(1, (t + 1) * 32);
        COMPUTE(0);
        __syncthreads();                    // drains buf1 stage; buf0 reads done
        if (t + 2 < 32) STAGE(0, (t + 2) * 32);
        COMPUTE(1);
        __syncthreads();                    // drains buf0 stage; buf1 reads done
    }
#undef STAGE
#undef COMPUTE

    // ---- fused second-layer epilogue (verified in R8) ----
    // seg 0: importance (cols 0-511, 1 output); seg 1: router (8); seg 2: unimp (8)
    const int seg = (bn < 4) ? 0 : (bn < 12 ? 1 : 2);
    const int half = wid & 1;               // which 64-col half this wave owns
    float w2v[4][8];
    float bcol[4];
#pragma unroll
    for (int nf = 0; nf < 4; nf++) {
        const int c = colBase + nw + nf * 16 + fr;
        bcol[nf] = bias_cat[c];
        if (seg == 0) {
            w2v[nf][0] = wi2[c];
        } else if (seg == 1) {
            const float4* w4 = (const float4*)&wr2[(c - 512) * 8];
            float4 a = w4[0], b = w4[1];
            w2v[nf][0] = a.x; w2v[nf][1] = a.y; w2v[nf][2] = a.z; w2v[nf][3] = a.w;
            w2v[nf][4] = b.x; w2v[nf][5] = b.y; w2v[nf][6] = b.z; w2v[nf][7] = b.w;
        } else {
            const float4* w4 = (const float4*)&wu2[(c - 1536) * 8];
            float4 a = w4[0], b = w4[1];
            w2v[nf][0] = a.x; w2v[nf][1] = a.y; w2v[nf][2] = a.z; w2v[nf][3] = a.w;
            w2v[nf][4] = b.x; w2v[nf][5] = b.y; w2v[nf][6] = b.z; w2v[nf][7] = b.w;
        }
    }

    const int tgroup = lane >> 4;           // 0..3
#pragma unroll
    for (int mf = 0; mf < 4; mf++) {
        const int tok0 = rowBase + mw + mf * 16 + tgroup * 4;
#pragma unroll
        for (int r = 0; r < 4; r++) {
            float sacc[8];
#pragma unroll
            for (int e = 0; e < 8; e++) sacc[e] = 0.f;
#pragma unroll
            for (int nf = 0; nf < 4; nf++) {
                float v = (acc_hh[mf][nf][r] + acc_x[mf][nf][r] * (1.0f / S_LO))
                          * (1.0f / S_W) + bcol[nf];
                v = fmaxf(v, 0.f);
                if (seg == 0) {
                    sacc[0] = fmaf(v, w2v[nf][0], sacc[0]);
                } else {
#pragma unroll
                    for (int e = 0; e < 8; e++)
                        sacc[e] = fmaf(v, w2v[nf][e], sacc[e]);
                }
            }
            const int nE = (seg == 0) ? 1 : 8;
            for (int e = 0; e < nE; e++) {
                float xv = sacc[e];
                xv += __shfl_xor(xv, 1, 64);
                xv += __shfl_xor(xv, 2, 64);
                xv += __shfl_xor(xv, 4, 64);
                xv += __shfl_xor(xv, 8, 64);
                if (fr == 0)
                    part[(((size_t)bn * 2 + half) * NTOK + (tok0 + r)) * 8 + e] = xv;
            }
        }
    }
}

// ---------------------------------------------------------------------------
// reduce_route: 16 blocks x 256 thr, one thread per token. Sums the 40
// per-(bn,half) partials, then sigmoid/mask/softmax/top-2.
// Slices: [0,8) importance, [8,24) router, [24,40) unimportant.
// ---------------------------------------------------------------------------
__global__ __launch_bounds__(256) void reduce_route(
    const float* __restrict__ part,
    const float* __restrict__ bi2, const float* __restrict__ br2,
    const float* __restrict__ bu2,
    float* __restrict__ oprobs, float* __restrict__ oimp,
    int* __restrict__ tke, float* __restrict__ tkp)
{
    const int t = blockIdx.x * 256 + threadIdx.x;    // 0..4095

    float imp = bi2[0];
#pragma unroll
    for (int sl = 0; sl < 8; sl++)
        imp += part[((size_t)sl * NTOK + t) * 8];

    float lr[8], lu[8];
#pragma unroll
    for (int e = 0; e < 8; e++) { lr[e] = br2[e]; lu[e] = bu2[e]; }
#pragma unroll
    for (int sl = 8; sl < 24; sl++) {
        const float4* p4 = (const float4*)&part[((size_t)sl * NTOK + t) * 8];
        float4 a = p4[0], b = p4[1];
        lr[0] += a.x; lr[1] += a.y; lr[2] += a.z; lr[3] += a.w;
        lr[4] += b.x; lr[5] += b.y; lr[6] += b.z; lr[7] += b.w;
    }
#pragma unroll
    for (int sl = 24; sl < 40; sl++) {
        const float4* p4 = (const float4*)&part[((size_t)sl * NTOK + t) * 8];
        float4 a = p4[0], b = p4[1];
        lu[0] += a.x; lu[1] += a.y; lu[2] += a.z; lu[3] += a.w;
        lu[4] += b.x; lu[5] += b.y; lu[6] += b.z; lu[7] += b.w;
    }

    const float sig = 1.f / (1.f + expf(-imp));
    oimp[t] = sig;
    const bool m = sig > 0.5f;
    float lg[8];
#pragma unroll
    for (int e = 0; e < 8; e++) lg[e] = m ? lr[e] : lu[e];

    float mx = lg[0];
#pragma unroll
    for (int e = 1; e < 8; e++) mx = fmaxf(mx, lg[e]);
    float p[8], sum = 0.f;
#pragma unroll
    for (int e = 0; e < 8; e++) { p[e] = expf(lg[e] - mx); sum += p[e]; }
    const float inv = 1.f / sum;
#pragma unroll
    for (int e = 0; e < 8; e++) { p[e] *= inv; oprobs[t * 8 + e] = p[e]; }

    int i1 = 0;
#pragma unroll
    for (int e = 1; e < 8; e++) if (p[e] > p[i1]) i1 = e;
    int i2 = (i1 == 0) ? 1 : 0;
#pragma unroll
    for (int e = 0; e < 8; e++) if (e != i1 && p[e] > p[i2]) i2 = e;
    const float ps = p[i1] + p[i2];
    tke[t]        = i1;
    tke[NTOK + t] = i2;
    tkp[t]        = p[i1] / ps;
    tkp[NTOK + t] = p[i2] / ps;
}

// ---------------------------------------------------------------------------
// Fused scan+scatter+aux: single block. k-major capacity assignment, writes
// <=8192 nonzeros into the pre-zeroed output, and computes the aux loss.
// ---------------------------------------------------------------------------
__global__ __launch_bounds__(256) void scan_scatter_aux(
    const int* __restrict__ tke, const float* __restrict__ tkp,
    const float* __restrict__ oprobs, const float* __restrict__ oimp,
    float* __restrict__ out, float* __restrict__ oaux)
{
    __shared__ unsigned char se[2 * NTOK];
    __shared__ float         sp[2 * NTOK];
    __shared__ int  cnts[256][8];
    __shared__ float red[4][16];

    const int tid = threadIdx.x;
    const int lane = tid & 63, wv = tid >> 6;

    for (int i = tid; i < 2 * NTOK; i += 256) {
        se[i] = (unsigned char)tke[i];
        sp[i] = tkp[i];
    }

    // ---- aux accumulation (independent of LDS staging above)
    float ap[8], ai[8];
#pragma unroll
    for (int e = 0; e < 8; e++) { ap[e] = 0.f; ai[e] = 0.f; }
    for (int t = tid; t < NTOK; t += 256) {
        const float msk = (oimp[t] > 0.5f) ? 1.f : 0.f;
#pragma unroll
        for (int e = 0; e < 8; e++) {
            float p = oprobs[t * 8 + e];
            ap[e] += p;
            ai[e] = fmaf(msk, p, ai[e]);
        }
    }
#pragma unroll
    for (int off = 32; off > 0; off >>= 1) {
#pragma unroll
        for (int e = 0; e < 8; e++) {
            ap[e] += __shfl_down(ap[e], off, 64);
            ai[e] += __shfl_down(ai[e], off, 64);
        }
    }
    if (lane == 0) {
#pragma unroll
        for (int e = 0; e < 8; e++) { red[wv][e] = ap[e]; red[wv][8 + e] = ai[e]; }
    }
    __syncthreads();
    if (tid == 0) {
        float ent = 0.f, tot = 0.f, isv[8];
#pragma unroll
        for (int e = 0; e < 8; e++) {
            float spr = red[0][e] + red[1][e] + red[2][e] + red[3][e];
            float sm  = red[0][8 + e] + red[1][8 + e] + red[2][8 + e] + red[3][8 + e];
            float r = spr / (float)NTOK;
            ent += r * logf(r * 8.f + 1e-9f);
            isv[e] = sm + 1e-9f;
            tot += isv[e];
        }
        float ie = 0.f;
#pragma unroll
        for (int e = 0; e < 8; e++) {
            float q = isv[e] / tot;
            ie -= q * logf(q + 1e-9f);
        }
        oaux[0] = ent - 0.1f * (ie / logf(8.f));
    }

    // ---- scan + scatter
    const int base = tid * 32;
    int c[8];
#pragma unroll
    for (int e = 0; e < 8; e++) c[e] = 0;
    for (int i = 0; i < 32; i++) {
        int e = se[base + i];
#pragma unroll
        for (int k = 0; k < 8; k++) c[k] += (e == k) ? 1 : 0;
    }
#pragma unroll
    for (int e = 0; e < 8; e++) cnts[tid][e] = c[e];
    __syncthreads();

    if (tid < 8) {
        int run = 0;
        for (int i = 0; i < 256; i++) {
            int v = cnts[i][tid];
            cnts[i][tid] = run;
            run += v;
        }
    }
    __syncthreads();

    int basecnt[8];
#pragma unroll
    for (int e = 0; e < 8; e++) basecnt[e] = cnts[tid][e];

    float* comb = out + (size_t)NTOK * NEXP * CAP;

    for (int i = 0; i < 32; i++) {
        const int idx = base + i;
        const int e = se[idx];
        int pos = 0;
#pragma unroll
        for (int k = 0; k < 8; k++)
            if (e == k) { pos = basecnt[k]; basecnt[k]++; }
        if (pos < CAP) {
            const int tok = idx & (NTOK - 1);
            const size_t o = ((size_t)tok * NEXP + e) * CAP + pos;
            out[o]  = 1.0f;
            comb[o] = sp[idx];
        }
    }
}

// ---------------------------------------------------------------------------
// Fallback path kernels (only used if ws is unexpectedly small)
// ---------------------------------------------------------------------------
__global__ __launch_bounds__(256) void gemm_bias_relu(
    const float* __restrict__ A, const float* __restrict__ B,
    const float* __restrict__ bias, float* __restrict__ Hout, int N)
{
    __shared__ float As[16][132];
    __shared__ float Bs[16][132];
    const int tid = threadIdx.x;
    const int tx = tid & 15, ty = tid >> 4;
    const int rowBase = blockIdx.y * 128, colBase = blockIdx.x * 128;
    const int lrow = tid >> 1, lkq = (tid & 1) * 8;
    const int bkk = tid >> 4, bcol = (tid & 15) * 8;
    float acc[8][8];
#pragma unroll
    for (int i = 0; i < 8; i++)
#pragma unroll
        for (int j = 0; j < 8; j++) acc[i][j] = 0.f;
    const float* Aptr = A + (size_t)(rowBase + lrow) * HDIM + lkq;
    const float* Bptr = B + (size_t)bkk * N + colBase + bcol;
    for (int k0 = 0; k0 < HDIM; k0 += 16) {
        float4 a0 = *(const float4*)(Aptr + k0);
        float4 a1 = *(const float4*)(Aptr + k0 + 4);
        float4 b0 = *(const float4*)(Bptr + (size_t)k0 * N);
        float4 b1 = *(const float4*)(Bptr + (size_t)k0 * N + 4);
        __syncthreads();
        As[lkq + 0][lrow] = a0.x; As[lkq + 1][lrow] = a0.y;
        As[lkq + 2][lrow] = a0.z; As[lkq + 3][lrow] = a0.w;
        As[lkq + 4][lrow] = a1.x; As[lkq + 5][lrow] = a1.y;
        As[lkq + 6][lrow] = a1.z; As[lkq + 7][lrow] = a1.w;
        *(float4*)&Bs[bkk][bcol] = b0;
        *(float4*)&Bs[bkk][bcol + 4] = b1;
        __syncthreads();
#pragma unroll
        for (int kk = 0; kk < 16; kk++) {
            float4 x0 = *(const float4*)&As[kk][ty * 8];
            float4 x1 = *(const float4*)&As[kk][ty * 8 + 4];
            float4 y0 = *(const float4*)&Bs[kk][tx * 8];
            float4 y1 = *(const float4*)&Bs[kk][tx * 8 + 4];
            float av[8] = {x0.x, x0.y, x0.z, x0.w, x1.x, x1.y, x1.z, x1.w};
            float bv[8] = {y0.x, y0.y, y0.z, y0.w, y1.x, y1.y, y1.z, y1.w};
#pragma unroll
            for (int i = 0; i < 8; i++)
#pragma unroll
                for (int j = 0; j < 8; j++)
                    acc[i][j] = fmaf(av[i], bv[j], acc[i][j]);
        }
    }
#pragma unroll
    for (int i = 0; i < 8; i++) {
        const int r = rowBase + ty * 8 + i, c = colBase + tx * 8;
#pragma unroll
        for (int j = 0; j < 8; j += 4) {
            float4 v;
            v.x = fmaxf(acc[i][j + 0] + bias[c + j + 0], 0.f);
            v.y = fmaxf(acc[i][j + 1] + bias[c + j + 1], 0.f);
            v.z = fmaxf(acc[i][j + 2] + bias[c + j + 2], 0.f);
            v.w = fmaxf(acc[i][j + 3] + bias[c + j + 3], 0.f);
            *(float4*)&Hout[(size_t)r * N + c + j] = v;
        }
    }
}

__global__ __launch_bounds__(256) void zerofill_fb(float* __restrict__ out)
{
    f32x4* o4 = (f32x4*)out;
    const unsigned total4 = TOTAL_DC / 4;
    unsigned i = blockIdx.x * 256u + threadIdx.x;
    const unsigned stride = gridDim.x * 256u;
    const f32x4 z = {0.f, 0.f, 0.f, 0.f};
    for (; i < total4; i += stride) o4[i] = z;
}

__global__ __launch_bounds__(256) void second_layer_sep(
    const float* __restrict__ h_i, const float* __restrict__ h_r,
    const float* __restrict__ h_u,
    const float* __restrict__ wi2, const float* __restrict__ bi2,
    const float* __restrict__ wr2, const float* __restrict__ br2,
    const float* __restrict__ wu2, const float* __restrict__ bu2,
    float* __restrict__ oprobs, float* __restrict__ oimp,
    int* __restrict__ tke, float* __restrict__ tkp)
{
    const int t = blockIdx.x;
    const int tid = threadIdx.x;
    float pi = 0.f;
    float pr[8], pu[8];
#pragma unroll
    for (int e = 0; e < 8; e++) { pr[e] = 0.f; pu[e] = 0.f; }
    const float* hi = h_i + (size_t)t * HHALF;
    const float* hr = h_r + (size_t)t * HDIM;
    const float* hu = h_u + (size_t)t * HDIM;
    for (int j = tid; j < HHALF; j += 256) pi = fmaf(hi[j], wi2[j], pi);
    for (int j = tid; j < HDIM; j += 256) {
        float a = hr[j], b = hu[j];
#pragma unroll
        for (int e = 0; e < 8; e++) {
            pr[e] = fmaf(a, wr2[j * 8 + e], pr[e]);
            pu[e] = fmaf(b, wu2[j * 8 + e], pu[e]);
        }
    }
#pragma unroll
    for (int off = 32; off > 0; off >>= 1) {
        pi += __shfl_down(pi, off, 64);
#pragma unroll
        for (int e = 0; e < 8; e++) {
            pr[e] += __shfl_down(pr[e], off, 64);
            pu[e] += __shfl_down(pu[e], off, 64);
        }
    }
    __shared__ float red[4][17];
    const int lane = tid & 63, wv = tid >> 6;
    if (lane == 0) {
        red[wv][0] = pi;
#pragma unroll
        for (int e = 0; e < 8; e++) { red[wv][1 + e] = pr[e]; red[wv][9 + e] = pu[e]; }
    }
    __syncthreads();
    if (tid == 0) {
        float si = red[0][0] + red[1][0] + red[2][0] + red[3][0] + bi2[0];
        float sig = 1.f / (1.f + expf(-si));
        oimp[t] = sig;
        const bool m = sig > 0.5f;
        float lg[8];
#pragma unroll
        for (int e = 0; e < 8; e++) {
            float vr = red[0][1 + e] + red[1][1 + e] + red[2][1 + e] + red[3][1 + e] + br2[e];
            float vu = red[0][9 + e] + red[1][9 + e] + red[2][9 + e] + red[3][9 + e] + bu2[e];
            lg[e] = m ? vr : vu;
        }
        float mx = lg[0];
#pragma unroll
        for (int e = 1; e < 8; e++) mx = fmaxf(mx, lg[e]);
        float p[8], s = 0.f;
#pragma unroll
        for (int e = 0; e < 8; e++) { p[e] = expf(lg[e] - mx); s += p[e]; }
        const float inv = 1.f / s;
#pragma unroll
        for (int e = 0; e < 8; e++) { p[e] *= inv; oprobs[t * 8 + e] = p[e]; }
        int i1 = 0;
#pragma unroll
        for (int e = 1; e < 8; e++) if (p[e] > p[i1]) i1 = e;
        int i2 = (i1 == 0) ? 1 : 0;
#pragma unroll
        for (int e = 0; e < 8; e++) if (e != i1 && p[e] > p[i2]) i2 = e;
        const float ps = p[i1] + p[i2];
        tke[t]        = i1;
        tke[NTOK + t] = i2;
        tkp[t]        = p[i1] / ps;
        tkp[NTOK + t] = p[i2] / ps;
    }
}

// ---------------------------------------------------------------------------
extern "C" void kernel_launch(void* const* d_in, const int* in_sizes, int n_in,
                              void* d_out, int out_size, void* d_ws, size_t ws_size,
                              hipStream_t stream) {
    const float* x   = (const float*)d_in[0];
    const float* wi1 = (const float*)d_in[1];
    const float* bi1 = (const float*)d_in[2];
    const float* wi2 = (const float*)d_in[3];
    const float* bi2 = (const float*)d_in[4];
    const float* wr1 = (const float*)d_in[5];
    const float* br1 = (const float*)d_in[6];
    const float* wr2 = (const float*)d_in[7];
    const float* br2 = (const float*)d_in[8];
    const float* wu1 = (const float*)d_in[9];
    const float* bu1 = (const float*)d_in[10];
    const float* wu2 = (const float*)d_in[11];
    const float* bu2 = (const float*)d_in[12];

    float* out    = (float*)d_out;
    float* oprobs = out + (size_t)TOTAL_DC;
    float* oaux   = oprobs + NTOK * NEXP;
    float* oimp   = oaux + 1;

    // ws layout: Ah,Al f16[4096*1024] | Bth,Btl f16[2560*1024] | bias f32[2560]
    //            | part f32[40*4096*8] | tke i32[8192] | tkp f32[8192]
    const size_t szA  = (size_t)NTOK * HDIM * 2;
    const size_t szB  = (size_t)NTOT * HDIM * 2;
    const size_t szP  = (size_t)40 * NTOK * 8 * 4;
    const size_t need = 2 * szA + 2 * szB + NTOT * 4 + szP
                      + 2 * NTOK * 4 + 2 * NTOK * 4 + 4096;
    dim3 blk(256);

    if (ws_size >= need) {
        char* p = (char*)d_ws;
        _Float16* Ah   = (_Float16*)p;         p += szA;
        _Float16* Al   = (_Float16*)p;         p += szA;
        _Float16* Bth  = (_Float16*)p;         p += szB;
        _Float16* Btl  = (_Float16*)p;         p += szB;
        float*    bias = (float*)p;            p += NTOT * 4;
        float*    part = (float*)p;            p += szP;
        int*      tke  = (int*)p;              p += 2 * NTOK * 4;
        float*    tkp  = (float*)p;

        prep<<<2689, blk, 0, stream>>>(x, wi1, wr1, wu1, bi1, br1, bu1,
                                       Ah, Al, Bth, Btl, bias);
        gemm_fill<<<2048, blk, 0, stream>>>(
            Ah, Al, Bth, Btl, bias, wi2, wr2, wu2, part, out);
        reduce_route<<<NTOK / 256, blk, 0, stream>>>(
            part, bi2, br2, bu2, oprobs, oimp, tke, tkp);
        scan_scatter_aux<<<1, blk, 0, stream>>>(tke, tkp, oprobs, oimp, out, oaux);
    } else {
        // fallback: fp32 GEMMs with activations in the dispatch region,
        // then zerofill + fused scan/scatter/aux.
        float* h_i = out;                                 // wiped by zerofill
        float* h_r = h_i + (size_t)NTOK * HHALF;
        float* h_u = h_r + (size_t)NTOK * HDIM;
        int*   tke  = (int*)d_ws;
        float* tkp  = (float*)d_ws + 2 * NTOK;

        gemm_bias_relu<<<dim3(HHALF / 128, NTOK / 128), blk, 0, stream>>>(x, wi1, bi1, h_i, HHALF);
        gemm_bias_relu<<<dim3(HDIM / 128, NTOK / 128), blk, 0, stream>>>(x, wr1, br1, h_r, HDIM);
        gemm_bias_relu<<<dim3(HDIM / 128, NTOK / 128), blk, 0, stream>>>(x, wu1, bu1, h_u, HDIM);
        second_layer_sep<<<NTOK, blk, 0, stream>>>(h_i, h_r, h_u, wi2, bi2, wr2, br2,
                                                   wu2, bu2, oprobs, oimp, tke, tkp);
        zerofill_fb<<<2048, blk, 0, stream>>>(out);
        scan_scatter_aux<<<1, blk, 0, stream>>>(tke, tkp, oprobs, oimp, out, oaux);
    }
}

// Round 13
// 188.568 us; speedup vs baseline: 1.1247x; 1.1247x over previous
//
#include <hip/hip_runtime.h>
#include <math.h>

#define HDIM  1024
#define HHALF 512
#define NEXP  8
#define NTOK  4096
#define CAP   1536
#define NTOT  2560                          // 512 + 1024 + 1024 concat output width
#define TOTAL_DC (2u * NTOK * NEXP * CAP)   // 100,663,296 floats (dispatch+combine)

typedef _Float16 f16x8 __attribute__((ext_vector_type(8)));
typedef float    f32x4 __attribute__((ext_vector_type(4)));

#define FILL_BLOCKS 1408
#define S_LO 2048.0f                        // lo-part scale (2^11)
#define S_W  32.0f                          // weight pre-scale

// ---------------------------------------------------------------------------
// prep: [0,2048) x -> A_hi/A_lo fp16 ; [2048,2688) weights -> Bt_hi/Bt_lo
// (transposed concat [2560][1024], pre-scaled x32) ; [2688] bias concat.
// ---------------------------------------------------------------------------
__global__ __launch_bounds__(256) void prep(
    const float* __restrict__ x,
    const float* __restrict__ wi1, const float* __restrict__ wr1,
    const float* __restrict__ wu1,
    const float* __restrict__ bi1, const float* __restrict__ br1,
    const float* __restrict__ bu1,
    _Float16* __restrict__ Ah, _Float16* __restrict__ Al,
    _Float16* __restrict__ Bth, _Float16* __restrict__ Btl,
    float* __restrict__ bias_cat)
{
    __shared__ float tile[64][65];
    const int bid = blockIdx.x, tid = threadIdx.x;

    if (bid < 2048) {                       // ---- x conversion, 8 elems/thread
        const int i8 = bid * 256 + tid;     // 0 .. 524287
        const float4* x4 = (const float4*)x;
        float4 v0 = x4[i8 * 2];
        float4 v1 = x4[i8 * 2 + 1];
        float f[8] = {v0.x, v0.y, v0.z, v0.w, v1.x, v1.y, v1.z, v1.w};
        f16x8 hi, lo;
#pragma unroll
        for (int j = 0; j < 8; j++) {
            _Float16 h = (_Float16)f[j];
            hi[j] = h;
            lo[j] = (_Float16)((f[j] - (float)h) * S_LO);
        }
        *(f16x8*)&Ah[(size_t)i8 * 8] = hi;
        *(f16x8*)&Al[(size_t)i8 * 8] = lo;
        return;
    }
    if (bid < 2688) {                       // ---- weight transpose+convert
        int local; const float* src; int C, nof;
        int b = bid - 2048;
        if (b < 128)      { src = wi1; C = 512;  nof = 0;    local = b; }
        else if (b < 384) { src = wr1; C = 1024; nof = 512;  local = b - 128; }
        else              { src = wu1; C = 1024; nof = 1536; local = b - 384; }
        const int nti = local >> 4, kti = local & 15;
#pragma unroll
        for (int p = 0; p < 16; p++) {
            int e = p * 256 + tid;
            int kr = e >> 6, nc = e & 63;
            tile[kr][nc] = src[(size_t)(kti * 64 + kr) * C + nti * 64 + nc];
        }
        __syncthreads();
#pragma unroll
        for (int p = 0; p < 16; p++) {
            int e = p * 256 + tid;
            int nl = e >> 6, kk = e & 63;
            float w32 = tile[kk][nl] * S_W;
            _Float16 h = (_Float16)w32;
            _Float16 l = (_Float16)((w32 - (float)h) * S_LO);
            const size_t o = (size_t)(nof + nti * 64 + nl) * 1024 + kti * 64 + kk;
            Bth[o] = h;
            Btl[o] = l;
        }
        return;
    }
    // ---- bias concat
    for (int i = tid; i < NTOT; i += 256) {
        float v = (i < 512) ? bi1[i] : (i < 1536) ? br1[i - 512] : bu1[i - 1536];
        bias_cat[i] = v;
    }
}

// ---------------------------------------------------------------------------
// gemm_fill: 2048 blocks in 256 octets of 8 (sub = blockIdx&7 = XCD).
// Octet groups of 8: first 11 groups = 7 GEMM octets + 1 fill octet; group 11
// = 3 GEMM + 5 fill; groups 12..31 = all fill. -> first 512 blocks are
// 448 GEMM + 64 fill, so the 402 MB zerofill streams under the GEMM phase.
// GEMM: fp16-split MFMA, 2-phase dbuf pipeline, XCD-sliced tiles, H output.
// ---------------------------------------------------------------------------
__global__ __launch_bounds__(256, 2) void gemm_fill(
    const _Float16* __restrict__ Ah, const _Float16* __restrict__ Al,
    const _Float16* __restrict__ Bth, const _Float16* __restrict__ Btl,
    const float* __restrict__ bias_cat, float* __restrict__ H,
    float* __restrict__ out)
{
    const int o = blockIdx.x >> 3, sub = blockIdx.x & 7;
    const int k = o >> 3, j = o & 7;        // octet group, position
    int g = -1, fo = 0;
    if (k < 11)       { if (j < 7) g = k * 7 + j; else fo = k; }
    else if (k == 11) { if (j < 3) g = 77 + j;    else fo = 11 + (j - 3); }
    else              { fo = 16 + ((k - 12) << 3) + j; }

    if (g < 0) {                            // ---------- fill path
        f32x4* o4 = (f32x4*)out;
        const unsigned total4 = TOTAL_DC / 4;            // 25,165,824
        unsigned i = (unsigned)(fo * 8 + sub) * 256u + threadIdx.x;
        const unsigned stride = FILL_BLOCKS * 256u;
        const f32x4 z = {0.f, 0.f, 0.f, 0.f};
        for (; i < total4; i += stride)
            __builtin_nontemporal_store(z, o4 + i);
        return;
    }

    __shared__ _Float16 lds[2][4][128][32];   // dbuf x {Ah|Al|Bh|Bl}, 64 KB

    const int tid = threadIdx.x;
    const int lane = tid & 63, wid = tid >> 6;

    // XCD-sliced mapping: xcd = sub; each XCD owns a bm-slice of 4, iterates
    // bm fastest so B panels are burst-reused.
    const int bm  = sub * 4 + (g & 3);        // 0..31
    const int bn  = g >> 2;                   // 0..19
    const int rowBase = bm * 128, colBase = bn * 128;

    // each wave stages its own tile type
    const _Float16* gb =
        (wid == 0) ? Ah  + (size_t)rowBase * 1024 :
        (wid == 1) ? Al  + (size_t)rowBase * 1024 :
        (wid == 2) ? Bth + (size_t)colBase * 1024 :
                     Btl + (size_t)colBase * 1024;
    const int lrow = lane >> 2;             // 0..15 within 16-row group
    // pre-swizzled 16B chunk within the 64B row (R11; bank-spread, neutral/safe)
    const int lkgs = (lane & 3) ^ ((lane >> 3) & 3);

    f32x4 acc_hh[4][4], acc_x[4][4];
    const f32x4 z4 = {0.f, 0.f, 0.f, 0.f};
#pragma unroll
    for (int i = 0; i < 4; i++)
#pragma unroll
        for (int j2 = 0; j2 < 4; j2++) { acc_hh[i][j2] = z4; acc_x[i][j2] = z4; }

    const int mw = (wid >> 1) * 64, nw = (wid & 1) * 64;
    const int fr = lane & 15, s = lane >> 4;
    const int rs = s ^ ((fr >> 1) & 3);     // swizzled read chunk

#define STAGE(buf, k0)                                                        \
    {                                                                         \
        _Pragma("unroll")                                                     \
        for (int i = 0; i < 8; i++) {                                         \
            const int r = i * 16 + lrow;                                      \
            __builtin_amdgcn_global_load_lds(                                 \
                (const void*)(gb + (size_t)r * 1024 + (k0) + lkgs * 8),       \
                (void*)&lds[buf][wid][i * 16][0], 16, 0, 0);                  \
        }                                                                     \
    }

#define COMPUTE(buf)                                                          \
    {                                                                         \
        f16x8 fa_h[4], fa_l[4], fb_h[4], fb_l[4];                             \
        _Pragma("unroll")                                                     \
        for (int mf = 0; mf < 4; mf++) {                                      \
            fa_h[mf] = *(const f16x8*)&lds[buf][0][mw + mf * 16 + fr][rs * 8];\
            fa_l[mf] = *(const f16x8*)&lds[buf][1][mw + mf * 16 + fr][rs * 8];\
        }                                                                     \
        _Pragma("unroll")                                                     \
        for (int nf = 0; nf < 4; nf++) {                                      \
            fb_h[nf] = *(const f16x8*)&lds[buf][2][nw + nf * 16 + fr][rs * 8];\
            fb_l[nf] = *(const f16x8*)&lds[buf][3][nw + nf * 16 + fr][rs * 8];\
        }                                                                     \
        _Pragma("unroll")                                                     \
        for (int mf = 0; mf < 4; mf++)                                        \
            _Pragma("unroll")                                                 \
            for (int nf = 0; nf < 4; nf++) {                                  \
                acc_hh[mf][nf] = __builtin_amdgcn_mfma_f32_16x16x32_f16(      \
                    fa_h[mf], fb_h[nf], acc_hh[mf][nf], 0, 0, 0);             \
                acc_x[mf][nf] = __builtin_amdgcn_mfma_f32_16x16x32_f16(       \
                    fa_h[mf], fb_l[nf], acc_x[mf][nf], 0, 0, 0);              \
                acc_x[mf][nf] = __builtin_amdgcn_mfma_f32_16x16x32_f16(       \
                    fa_l[mf], fb_h[nf], acc_x[mf][nf], 0, 0, 0);              \
            }                                                                 \
    }

    STAGE(0, 0);
    __syncthreads();                        // buf0 staged

    for (int t = 0; t < 32; t += 2) {
        if (t + 1 < 32) STAGE(1, (t + 1) * 32);
        COMPUTE(0);
        __syncthreads();                    // drains buf1 stage; buf0 reads done
        if (t + 2 < 32) STAGE(0, (t + 2) * 32);
        COMPUTE(1);
        __syncthreads();                    // drains buf0 stage; buf1 reads done
    }
#undef STAGE
#undef COMPUTE

    // epilogue: v = (hh + x/2048)/32 + bias, relu -> H
#pragma unroll
    for (int mf = 0; mf < 4; mf++) {
        const int row0 = rowBase + mw + mf * 16 + (lane >> 4) * 4;
#pragma unroll
        for (int nf = 0; nf < 4; nf++) {
            const int col = colBase + nw + nf * 16 + (lane & 15);
            const float b = bias_cat[col];
#pragma unroll
            for (int r = 0; r < 4; r++) {
                float v = (acc_hh[mf][nf][r] + acc_x[mf][nf][r] * (1.0f / S_LO))
                          * (1.0f / S_W) + b;
                H[(size_t)(row0 + r) * NTOT + col] = fmaxf(v, 0.f);
            }
        }
    }
}

// ---------------------------------------------------------------------------
// Per-token second layer on concat H [4096][2560], float4-vectorized reads.
// One block (256 thr) per token.
// ---------------------------------------------------------------------------
__global__ __launch_bounds__(256) void second_layer(
    const float* __restrict__ H,
    const float* __restrict__ wi2, const float* __restrict__ bi2,
    const float* __restrict__ wr2, const float* __restrict__ br2,
    const float* __restrict__ wu2, const float* __restrict__ bu2,
    float* __restrict__ oprobs, float* __restrict__ oimp,
    int* __restrict__ tke, float* __restrict__ tkp)
{
    const int t = blockIdx.x;
    const int tid = threadIdx.x;
    const float4* h4 = (const float4*)(H + (size_t)t * NTOT);

    float pi = 0.f;
    float pr[8], pu[8];
#pragma unroll
    for (int e = 0; e < 8; e++) { pr[e] = 0.f; pu[e] = 0.f; }

    // importance: cols [0,512) = h4[0..127], threads 0..127
    if (tid < 128) {
        float4 v = h4[tid];
        float4 w = ((const float4*)wi2)[tid];
        pi = v.x * w.x + v.y * w.y + v.z * w.z + v.w * w.w;
    }
    // router: cols [512,1536) = h4[128..383]; one float4 per thread
    {
        float4 v = h4[128 + tid];
        const int j = tid * 4;              // col - 512
        const float4* w4 = (const float4*)&wr2[(size_t)j * 8];
#pragma unroll
        for (int q = 0; q < 4; q++) {
            const float hv = (q == 0) ? v.x : (q == 1) ? v.y : (q == 2) ? v.z : v.w;
            float4 a = w4[q * 2], b = w4[q * 2 + 1];
            pr[0] = fmaf(hv, a.x, pr[0]); pr[1] = fmaf(hv, a.y, pr[1]);
            pr[2] = fmaf(hv, a.z, pr[2]); pr[3] = fmaf(hv, a.w, pr[3]);
            pr[4] = fmaf(hv, b.x, pr[4]); pr[5] = fmaf(hv, b.y, pr[5]);
            pr[6] = fmaf(hv, b.z, pr[6]); pr[7] = fmaf(hv, b.w, pr[7]);
        }
    }
    // unimportant: cols [1536,2560) = h4[384..639]
    {
        float4 v = h4[384 + tid];
        const int j = tid * 4;              // col - 1536
        const float4* w4 = (const float4*)&wu2[(size_t)j * 8];
#pragma unroll
        for (int q = 0; q < 4; q++) {
            const float hv = (q == 0) ? v.x : (q == 1) ? v.y : (q == 2) ? v.z : v.w;
            float4 a = w4[q * 2], b = w4[q * 2 + 1];
            pu[0] = fmaf(hv, a.x, pu[0]); pu[1] = fmaf(hv, a.y, pu[1]);
            pu[2] = fmaf(hv, a.z, pu[2]); pu[3] = fmaf(hv, a.w, pu[3]);
            pu[4] = fmaf(hv, b.x, pu[4]); pu[5] = fmaf(hv, b.y, pu[5]);
            pu[6] = fmaf(hv, b.z, pu[6]); pu[7] = fmaf(hv, b.w, pu[7]);
        }
    }

#pragma unroll
    for (int off = 32; off > 0; off >>= 1) {
        pi += __shfl_down(pi, off, 64);
#pragma unroll
        for (int e = 0; e < 8; e++) {
            pr[e] += __shfl_down(pr[e], off, 64);
            pu[e] += __shfl_down(pu[e], off, 64);
        }
    }

    __shared__ float red[4][17];
    const int lane = tid & 63, wv = tid >> 6;
    if (lane == 0) {
        red[wv][0] = pi;
#pragma unroll
        for (int e = 0; e < 8; e++) { red[wv][1 + e] = pr[e]; red[wv][9 + e] = pu[e]; }
    }
    __syncthreads();

    if (tid == 0) {
        float si = red[0][0] + red[1][0] + red[2][0] + red[3][0] + bi2[0];
        float sig = 1.f / (1.f + expf(-si));
        oimp[t] = sig;
        const bool m = sig > 0.5f;
        float lg[8];
#pragma unroll
        for (int e = 0; e < 8; e++) {
            float vr = red[0][1 + e] + red[1][1 + e] + red[2][1 + e] + red[3][1 + e] + br2[e];
            float vu = red[0][9 + e] + red[1][9 + e] + red[2][9 + e] + red[3][9 + e] + bu2[e];
            lg[e] = m ? vr : vu;
        }
        float mx = lg[0];
#pragma unroll
        for (int e = 1; e < 8; e++) mx = fmaxf(mx, lg[e]);
        float p[8], sum = 0.f;
#pragma unroll
        for (int e = 0; e < 8; e++) { p[e] = expf(lg[e] - mx); sum += p[e]; }
        const float inv = 1.f / sum;
#pragma unroll
        for (int e = 0; e < 8; e++) { p[e] *= inv; oprobs[t * 8 + e] = p[e]; }
        int i1 = 0;
#pragma unroll
        for (int e = 1; e < 8; e++) if (p[e] > p[i1]) i1 = e;
        int i2 = (i1 == 0) ? 1 : 0;
#pragma unroll
        for (int e = 0; e < 8; e++) if (e != i1 && p[e] > p[i2]) i2 = e;
        const float ps = p[i1] + p[i2];
        tke[t]        = i1;
        tke[NTOK + t] = i2;
        tkp[t]        = p[i1] / ps;
        tkp[NTOK + t] = p[i2] / ps;
    }
}

// ---------------------------------------------------------------------------
// Fused scan+scatter+aux: single block. k-major capacity assignment, writes
// <=8192 nonzeros into the pre-zeroed output, and computes the aux loss.
// ---------------------------------------------------------------------------
__global__ __launch_bounds__(256) void scan_scatter_aux(
    const int* __restrict__ tke, const float* __restrict__ tkp,
    const float* __restrict__ oprobs, const float* __restrict__ oimp,
    float* __restrict__ out, float* __restrict__ oaux)
{
    __shared__ unsigned char se[2 * NTOK];
    __shared__ float         sp[2 * NTOK];
    __shared__ int  cnts[256][8];
    __shared__ float red[4][16];

    const int tid = threadIdx.x;
    const int lane = tid & 63, wv = tid >> 6;

    for (int i = tid; i < 2 * NTOK; i += 256) {
        se[i] = (unsigned char)tke[i];
        sp[i] = tkp[i];
    }

    // ---- aux accumulation (independent of LDS staging above)
    float ap[8], ai[8];
#pragma unroll
    for (int e = 0; e < 8; e++) { ap[e] = 0.f; ai[e] = 0.f; }
    for (int t = tid; t < NTOK; t += 256) {
        const float msk = (oimp[t] > 0.5f) ? 1.f : 0.f;
#pragma unroll
        for (int e = 0; e < 8; e++) {
            float p = oprobs[t * 8 + e];
            ap[e] += p;
            ai[e] = fmaf(msk, p, ai[e]);
        }
    }
#pragma unroll
    for (int off = 32; off > 0; off >>= 1) {
#pragma unroll
        for (int e = 0; e < 8; e++) {
            ap[e] += __shfl_down(ap[e], off, 64);
            ai[e] += __shfl_down(ai[e], off, 64);
        }
    }
    if (lane == 0) {
#pragma unroll
        for (int e = 0; e < 8; e++) { red[wv][e] = ap[e]; red[wv][8 + e] = ai[e]; }
    }
    __syncthreads();
    if (tid == 0) {
        float ent = 0.f, tot = 0.f, isv[8];
#pragma unroll
        for (int e = 0; e < 8; e++) {
            float spr = red[0][e] + red[1][e] + red[2][e] + red[3][e];
            float sm  = red[0][8 + e] + red[1][8 + e] + red[2][8 + e] + red[3][8 + e];
            float r = spr / (float)NTOK;
            ent += r * logf(r * 8.f + 1e-9f);
            isv[e] = sm + 1e-9f;
            tot += isv[e];
        }
        float ie = 0.f;
#pragma unroll
        for (int e = 0; e < 8; e++) {
            float q = isv[e] / tot;
            ie -= q * logf(q + 1e-9f);
        }
        oaux[0] = ent - 0.1f * (ie / logf(8.f));
    }

    // ---- scan + scatter
    const int base = tid * 32;
    int c[8];
#pragma unroll
    for (int e = 0; e < 8; e++) c[e] = 0;
    for (int i = 0; i < 32; i++) {
        int e = se[base + i];
#pragma unroll
        for (int k = 0; k < 8; k++) c[k] += (e == k) ? 1 : 0;
    }
#pragma unroll
    for (int e = 0; e < 8; e++) cnts[tid][e] = c[e];
    __syncthreads();

    if (tid < 8) {
        int run = 0;
        for (int i = 0; i < 256; i++) {
            int v = cnts[i][tid];
            cnts[i][tid] = run;
            run += v;
        }
    }
    __syncthreads();

    int basecnt[8];
#pragma unroll
    for (int e = 0; e < 8; e++) basecnt[e] = cnts[tid][e];

    float* comb = out + (size_t)NTOK * NEXP * CAP;

    for (int i = 0; i < 32; i++) {
        const int idx = base + i;
        const int e = se[idx];
        int pos = 0;
#pragma unroll
        for (int k = 0; k < 8; k++)
            if (e == k) { pos = basecnt[k]; basecnt[k]++; }
        if (pos < CAP) {
            const int tok = idx & (NTOK - 1);
            const size_t o = ((size_t)tok * NEXP + e) * CAP + pos;
            out[o]  = 1.0f;
            comb[o] = sp[idx];
        }
    }
}

// ---------------------------------------------------------------------------
// Fallback path kernels (only used if ws is unexpectedly small)
// ---------------------------------------------------------------------------
__global__ __launch_bounds__(256) void gemm_bias_relu(
    const float* __restrict__ A, const float* __restrict__ B,
    const float* __restrict__ bias, float* __restrict__ Hout, int N)
{
    __shared__ float As[16][132];
    __shared__ float Bs[16][132];
    const int tid = threadIdx.x;
    const int tx = tid & 15, ty = tid >> 4;
    const int rowBase = blockIdx.y * 128, colBase = blockIdx.x * 128;
    const int lrow = tid >> 1, lkq = (tid & 1) * 8;
    const int bkk = tid >> 4, bcol = (tid & 15) * 8;
    float acc[8][8];
#pragma unroll
    for (int i = 0; i < 8; i++)
#pragma unroll
        for (int j = 0; j < 8; j++) acc[i][j] = 0.f;
    const float* Aptr = A + (size_t)(rowBase + lrow) * HDIM + lkq;
    const float* Bptr = B + (size_t)bkk * N + colBase + bcol;
    for (int k0 = 0; k0 < HDIM; k0 += 16) {
        float4 a0 = *(const float4*)(Aptr + k0);
        float4 a1 = *(const float4*)(Aptr + k0 + 4);
        float4 b0 = *(const float4*)(Bptr + (size_t)k0 * N);
        float4 b1 = *(const float4*)(Bptr + (size_t)k0 * N + 4);
        __syncthreads();
        As[lkq + 0][lrow] = a0.x; As[lkq + 1][lrow] = a0.y;
        As[lkq + 2][lrow] = a0.z; As[lkq + 3][lrow] = a0.w;
        As[lkq + 4][lrow] = a1.x; As[lkq + 5][lrow] = a1.y;
        As[lkq + 6][lrow] = a1.z; As[lkq + 7][lrow] = a1.w;
        *(float4*)&Bs[bkk][bcol] = b0;
        *(float4*)&Bs[bkk][bcol + 4] = b1;
        __syncthreads();
#pragma unroll
        for (int kk = 0; kk < 16; kk++) {
            float4 x0 = *(const float4*)&As[kk][ty * 8];
            float4 x1 = *(const float4*)&As[kk][ty * 8 + 4];
            float4 y0 = *(const float4*)&Bs[kk][tx * 8];
            float4 y1 = *(const float4*)&Bs[kk][tx * 8 + 4];
            float av[8] = {x0.x, x0.y, x0.z, x0.w, x1.x, x1.y, x1.z, x1.w};
            float bv[8] = {y0.x, y0.y, y0.z, y0.w, y1.x, y1.y, y1.z, y1.w};
#pragma unroll
            for (int i = 0; i < 8; i++)
#pragma unroll
                for (int j = 0; j < 8; j++)
                    acc[i][j] = fmaf(av[i], bv[j], acc[i][j]);
        }
    }
#pragma unroll
    for (int i = 0; i < 8; i++) {
        const int r = rowBase + ty * 8 + i, c = colBase + tx * 8;
#pragma unroll
        for (int j = 0; j < 8; j += 4) {
            float4 v;
            v.x = fmaxf(acc[i][j + 0] + bias[c + j + 0], 0.f);
            v.y = fmaxf(acc[i][j + 1] + bias[c + j + 1], 0.f);
            v.z = fmaxf(acc[i][j + 2] + bias[c + j + 2], 0.f);
            v.w = fmaxf(acc[i][j + 3] + bias[c + j + 3], 0.f);
            *(float4*)&Hout[(size_t)r * N + c + j] = v;
        }
    }
}

__global__ __launch_bounds__(256) void zerofill_fb(float* __restrict__ out)
{
    f32x4* o4 = (f32x4*)out;
    const unsigned total4 = TOTAL_DC / 4;
    unsigned i = blockIdx.x * 256u + threadIdx.x;
    const unsigned stride = gridDim.x * 256u;
    const f32x4 z = {0.f, 0.f, 0.f, 0.f};
    for (; i < total4; i += stride) o4[i] = z;
}

__global__ __launch_bounds__(256) void second_layer_sep(
    const float* __restrict__ h_i, const float* __restrict__ h_r,
    const float* __restrict__ h_u,
    const float* __restrict__ wi2, const float* __restrict__ bi2,
    const float* __restrict__ wr2, const float* __restrict__ br2,
    const float* __restrict__ wu2, const float* __restrict__ bu2,
    float* __restrict__ oprobs, float* __restrict__ oimp,
    int* __restrict__ tke, float* __restrict__ tkp)
{
    const int t = blockIdx.x;
    const int tid = threadIdx.x;
    float pi = 0.f;
    float pr[8], pu[8];
#pragma unroll
    for (int e = 0; e < 8; e++) { pr[e] = 0.f; pu[e] = 0.f; }
    const float* hi = h_i + (size_t)t * HHALF;
    const float* hr = h_r + (size_t)t * HDIM;
    const float* hu = h_u + (size_t)t * HDIM;
    for (int j = tid; j < HHALF; j += 256) pi = fmaf(hi[j], wi2[j], pi);
    for (int j = tid; j < HDIM; j += 256) {
        float a = hr[j], b = hu[j];
#pragma unroll
        for (int e = 0; e < 8; e++) {
            pr[e] = fmaf(a, wr2[j * 8 + e], pr[e]);
            pu[e] = fmaf(b, wu2[j * 8 + e], pu[e]);
        }
    }
#pragma unroll
    for (int off = 32; off > 0; off >>= 1) {
        pi += __shfl_down(pi, off, 64);
#pragma unroll
        for (int e = 0; e < 8; e++) {
            pr[e] += __shfl_down(pr[e], off, 64);
            pu[e] += __shfl_down(pu[e], off, 64);
        }
    }
    __shared__ float red[4][17];
    const int lane = tid & 63, wv = tid >> 6;
    if (lane == 0) {
        red[wv][0] = pi;
#pragma unroll
        for (int e = 0; e < 8; e++) { red[wv][1 + e] = pr[e]; red[wv][9 + e] = pu[e]; }
    }
    __syncthreads();
    if (tid == 0) {
        float si = red[0][0] + red[1][0] + red[2][0] + red[3][0] + bi2[0];
        float sig = 1.f / (1.f + expf(-si));
        oimp[t] = sig;
        const bool m = sig > 0.5f;
        float lg[8];
#pragma unroll
        for (int e = 0; e < 8; e++) {
            float vr = red[0][1 + e] + red[1][1 + e] + red[2][1 + e] + red[3][1 + e] + br2[e];
            float vu = red[0][9 + e] + red[1][9 + e] + red[2][9 + e] + red[9 > 8 ? 3 : 3][9 + e] * 0.f + red[3][9 + e] + bu2[e];
            lg[e] = m ? vr : vu;
        }
        float mx = lg[0];
#pragma unroll
        for (int e = 1; e < 8; e++) mx = fmaxf(mx, lg[e]);
        float p[8], s = 0.f;
#pragma unroll
        for (int e = 0; e < 8; e++) { p[e] = expf(lg[e] - mx); s += p[e]; }
        const float inv = 1.f / s;
#pragma unroll
        for (int e = 0; e < 8; e++) { p[e] *= inv; oprobs[t * 8 + e] = p[e]; }
        int i1 = 0;
#pragma unroll
        for (int e = 1; e < 8; e++) if (p[e] > p[i1]) i1 = e;
        int i2 = (i1 == 0) ? 1 : 0;
#pragma unroll
        for (int e = 0; e < 8; e++) if (e != i1 && p[e] > p[i2]) i2 = e;
        const float ps = p[i1] + p[i2];
        tke[t]        = i1;
        tke[NTOK + t] = i2;
        tkp[t]        = p[i1] / ps;
        tkp[NTOK + t] = p[i2] / ps;
    }
}

// ---------------------------------------------------------------------------
extern "C" void kernel_launch(void* const* d_in, const int* in_sizes, int n_in,
                              void* d_out, int out_size, void* d_ws, size_t ws_size,
                              hipStream_t stream) {
    const float* x   = (const float*)d_in[0];
    const float* wi1 = (const float*)d_in[1];
    const float* bi1 = (const float*)d_in[2];
    const float* wi2 = (const float*)d_in[3];
    const float* bi2 = (const float*)d_in[4];
    const float* wr1 = (const float*)d_in[5];
    const float* br1 = (const float*)d_in[6];
    const float* wr2 = (const float*)d_in[7];
    const float* br2 = (const float*)d_in[8];
    const float* wu1 = (const float*)d_in[9];
    const float* bu1 = (const float*)d_in[10];
    const float* wu2 = (const float*)d_in[11];
    const float* bu2 = (const float*)d_in[12];

    float* out    = (float*)d_out;
    float* oprobs = out + (size_t)TOTAL_DC;
    float* oaux   = oprobs + NTOK * NEXP;
    float* oimp   = oaux + 1;

    // ws layout: H f32[4096*2560] | Ah,Al f16[4096*1024] | Bth,Btl f16[2560*1024]
    //            | bias f32[2560] | tke i32[8192] | tkp f32[8192]
    const size_t szH  = (size_t)NTOK * NTOT * 4;
    const size_t szA  = (size_t)NTOK * HDIM * 2;
    const size_t szB  = (size_t)NTOT * HDIM * 2;
    const size_t need = szH + 2 * szA + 2 * szB + NTOT * 4
                      + 2 * NTOK * 4 + 2 * NTOK * 4 + 4096;
    dim3 blk(256);

    if (ws_size >= need) {
        char* p = (char*)d_ws;
        float*    H    = (float*)p;            p += szH;
        _Float16* Ah   = (_Float16*)p;         p += szA;
        _Float16* Al   = (_Float16*)p;         p += szA;
        _Float16* Bth  = (_Float16*)p;         p += szB;
        _Float16* Btl  = (_Float16*)p;         p += szB;
        float*    bias = (float*)p;            p += NTOT * 4;
        int*      tke  = (int*)p;              p += 2 * NTOK * 4;
        float*    tkp  = (float*)p;

        prep<<<2689, blk, 0, stream>>>(x, wi1, wr1, wu1, bi1, br1, bu1,
                                       Ah, Al, Bth, Btl, bias);
        gemm_fill<<<2048, blk, 0, stream>>>(
            Ah, Al, Bth, Btl, bias, H, out);
        second_layer<<<NTOK, blk, 0, stream>>>(H, wi2, bi2, wr2, br2, wu2, bu2,
                                               oprobs, oimp, tke, tkp);
        scan_scatter_aux<<<1, blk, 0, stream>>>(tke, tkp, oprobs, oimp, out, oaux);
    } else {
        // fallback: fp32 GEMMs with activations in the dispatch region,
        // then zerofill + fused scan/scatter/aux.
        float* h_i = out;                                 // wiped by zerofill
        float* h_r = h_i + (size_t)NTOK * HHALF;
        float* h_u = h_r + (size_t)NTOK * HDIM;
        int*   tke  = (int*)d_ws;
        float* tkp  = (float*)d_ws + 2 * NTOK;

        gemm_bias_relu<<<dim3(HHALF / 128, NTOK / 128), blk, 0, stream>>>(x, wi1, bi1, h_i, HHALF);
        gemm_bias_relu<<<dim3(HDIM / 128, NTOK / 128), blk, 0, stream>>>(x, wr1, br1, h_r, HDIM);
        gemm_bias_relu<<<dim3(HDIM / 128, NTOK / 128), blk, 0, stream>>>(x, wu1, bu1, h_u, HDIM);
        second_layer_sep<<<NTOK, blk, 0, stream>>>(h_i, h_r, h_u, wi2, bi2, wr2, br2,
                                                   wu2, bu2, oprobs, oimp, tke, tkp);
        zerofill_fb<<<2048, blk, 0, stream>>>(out);
        scan_scatter_aux<<<1, blk, 0, stream>>>(tke, tkp, oprobs, oimp, out, oaux);
    }
}

// Round 14
// 177.291 us; speedup vs baseline: 1.1963x; 1.0636x over previous
//
#include <hip/hip_runtime.h>
#include <math.h>

#define HDIM  1024
#define HHALF 512
#define NEXP  8
#define NTOK  4096
#define CAP   1536
#define NTOT  2560                          // 512 + 1024 + 1024 concat output width
#define TOTAL_DC (2u * NTOK * NEXP * CAP)   // 100,663,296 floats (dispatch+combine)

typedef _Float16 f16x8 __attribute__((ext_vector_type(8)));
typedef float    f32x4 __attribute__((ext_vector_type(4)));

#define FILL_BLOCKS 1408
#define S_LO 2048.0f                        // lo-part scale (2^11)
#define S_W  32.0f                          // weight pre-scale

// ---------------------------------------------------------------------------
// prep: [0,2048) x -> A_hi/A_lo fp16 ; [2048,2688) weights -> Bt_hi/Bt_lo
// (transposed concat [2560][1024], pre-scaled x32) ; [2688] bias concat.
// ---------------------------------------------------------------------------
__global__ __launch_bounds__(256) void prep(
    const float* __restrict__ x,
    const float* __restrict__ wi1, const float* __restrict__ wr1,
    const float* __restrict__ wu1,
    const float* __restrict__ bi1, const float* __restrict__ br1,
    const float* __restrict__ bu1,
    _Float16* __restrict__ Ah, _Float16* __restrict__ Al,
    _Float16* __restrict__ Bth, _Float16* __restrict__ Btl,
    float* __restrict__ bias_cat)
{
    __shared__ float tile[64][65];
    const int bid = blockIdx.x, tid = threadIdx.x;

    if (bid < 2048) {                       // ---- x conversion, 8 elems/thread
        const int i8 = bid * 256 + tid;     // 0 .. 524287
        const float4* x4 = (const float4*)x;
        float4 v0 = x4[i8 * 2];
        float4 v1 = x4[i8 * 2 + 1];
        float f[8] = {v0.x, v0.y, v0.z, v0.w, v1.x, v1.y, v1.z, v1.w};
        f16x8 hi, lo;
#pragma unroll
        for (int j = 0; j < 8; j++) {
            _Float16 h = (_Float16)f[j];
            hi[j] = h;
            lo[j] = (_Float16)((f[j] - (float)h) * S_LO);
        }
        *(f16x8*)&Ah[(size_t)i8 * 8] = hi;
        *(f16x8*)&Al[(size_t)i8 * 8] = lo;
        return;
    }
    if (bid < 2688) {                       // ---- weight transpose+convert
        int local; const float* src; int C, nof;
        int b = bid - 2048;
        if (b < 128)      { src = wi1; C = 512;  nof = 0;    local = b; }
        else if (b < 384) { src = wr1; C = 1024; nof = 512;  local = b - 128; }
        else              { src = wu1; C = 1024; nof = 1536; local = b - 384; }
        const int nti = local >> 4, kti = local & 15;
#pragma unroll
        for (int p = 0; p < 16; p++) {
            int e = p * 256 + tid;
            int kr = e >> 6, nc = e & 63;
            tile[kr][nc] = src[(size_t)(kti * 64 + kr) * C + nti * 64 + nc];
        }
        __syncthreads();
#pragma unroll
        for (int p = 0; p < 16; p++) {
            int e = p * 256 + tid;
            int nl = e >> 6, kk = e & 63;
            float w32 = tile[kk][nl] * S_W;
            _Float16 h = (_Float16)w32;
            _Float16 l = (_Float16)((w32 - (float)h) * S_LO);
            const size_t o = (size_t)(nof + nti * 64 + nl) * 1024 + kti * 64 + kk;
            Bth[o] = h;
            Btl[o] = l;
        }
        return;
    }
    // ---- bias concat
    for (int i = tid; i < NTOT; i += 256) {
        float v = (i < 512) ? bi1[i] : (i < 1536) ? br1[i - 512] : bu1[i - 1536];
        bias_cat[i] = v;
    }
}

// ---------------------------------------------------------------------------
// gemm_fill: 2048 blocks in 256 octets of 8 (sub = blockIdx&7 = XCD).
// Octet groups of 8: first 11 groups = 7 GEMM octets + 1 fill octet; group 11
// = 3 GEMM + 5 fill; groups 12..31 = all fill. -> first 512 blocks are
// 448 GEMM + 64 fill, so the 402 MB zerofill streams under the GEMM phase.
// GEMM: fp16-split MFMA, 2-phase dbuf pipeline, XCD-sliced tiles, H output.
// ---------------------------------------------------------------------------
__global__ __launch_bounds__(256, 2) void gemm_fill(
    const _Float16* __restrict__ Ah, const _Float16* __restrict__ Al,
    const _Float16* __restrict__ Bth, const _Float16* __restrict__ Btl,
    const float* __restrict__ bias_cat, float* __restrict__ H,
    float* __restrict__ out)
{
    const int o = blockIdx.x >> 3, sub = blockIdx.x & 7;
    const int k = o >> 3, j = o & 7;        // octet group, position
    int g = -1, fo = 0;
    if (k < 11)       { if (j < 7) g = k * 7 + j; else fo = k; }
    else if (k == 11) { if (j < 3) g = 77 + j;    else fo = 11 + (j - 3); }
    else              { fo = 16 + ((k - 12) << 3) + j; }

    if (g < 0) {                            // ---------- fill path
        f32x4* o4 = (f32x4*)out;
        const unsigned total4 = TOTAL_DC / 4;            // 25,165,824
        unsigned i = (unsigned)(fo * 8 + sub) * 256u + threadIdx.x;
        const unsigned stride = FILL_BLOCKS * 256u;
        const f32x4 z = {0.f, 0.f, 0.f, 0.f};
        for (; i < total4; i += stride)
            __builtin_nontemporal_store(z, o4 + i);
        return;
    }

    __shared__ _Float16 lds[2][4][128][32];   // dbuf x {Ah|Al|Bh|Bl}, 64 KB

    const int tid = threadIdx.x;
    const int lane = tid & 63, wid = tid >> 6;

    // XCD-sliced mapping: xcd = sub; each XCD owns a bm-slice of 4, iterates
    // bm fastest so B panels are burst-reused.
    const int bm  = sub * 4 + (g & 3);        // 0..31
    const int bn  = g >> 2;                   // 0..19
    const int rowBase = bm * 128, colBase = bn * 128;

    // each wave stages its own tile type
    const _Float16* gb =
        (wid == 0) ? Ah  + (size_t)rowBase * 1024 :
        (wid == 1) ? Al  + (size_t)rowBase * 1024 :
        (wid == 2) ? Bth + (size_t)colBase * 1024 :
                     Btl + (size_t)colBase * 1024;
    const int lrow = lane >> 2;             // 0..15 within 16-row group
    // pre-swizzled 16B chunk within the 64B row (bank-spread, neutral/safe)
    const int lkgs = (lane & 3) ^ ((lane >> 3) & 3);

    f32x4 acc_hh[4][4], acc_x[4][4];
    const f32x4 z4 = {0.f, 0.f, 0.f, 0.f};
#pragma unroll
    for (int i = 0; i < 4; i++)
#pragma unroll
        for (int j2 = 0; j2 < 4; j2++) { acc_hh[i][j2] = z4; acc_x[i][j2] = z4; }

    const int mw = (wid >> 1) * 64, nw = (wid & 1) * 64;
    const int fr = lane & 15, s = lane >> 4;
    const int rs = s ^ ((fr >> 1) & 3);     // swizzled read chunk

#define STAGE(buf, k0)                                                        \
    {                                                                         \
        _Pragma("unroll")                                                     \
        for (int i = 0; i < 8; i++) {                                         \
            const int r = i * 16 + lrow;                                      \
            __builtin_amdgcn_global_load_lds(                                 \
                (const void*)(gb + (size_t)r * 1024 + (k0) + lkgs * 8),       \
                (void*)&lds[buf][wid][i * 16][0], 16, 0, 0);                  \
        }                                                                     \
    }

#define COMPUTE(buf)                                                          \
    {                                                                         \
        f16x8 fa_h[4], fa_l[4], fb_h[4], fb_l[4];                             \
        _Pragma("unroll")                                                     \
        for (int mf = 0; mf < 4; mf++) {                                      \
            fa_h[mf] = *(const f16x8*)&lds[buf][0][mw + mf * 16 + fr][rs * 8];\
            fa_l[mf] = *(const f16x8*)&lds[buf][1][mw + mf * 16 + fr][rs * 8];\
        }                                                                     \
        _Pragma("unroll")                                                     \
        for (int nf = 0; nf < 4; nf++) {                                      \
            fb_h[nf] = *(const f16x8*)&lds[buf][2][nw + nf * 16 + fr][rs * 8];\
            fb_l[nf] = *(const f16x8*)&lds[buf][3][nw + nf * 16 + fr][rs * 8];\
        }                                                                     \
        _Pragma("unroll")                                                     \
        for (int mf = 0; mf < 4; mf++)                                        \
            _Pragma("unroll")                                                 \
            for (int nf = 0; nf < 4; nf++) {                                  \
                acc_hh[mf][nf] = __builtin_amdgcn_mfma_f32_16x16x32_f16(      \
                    fa_h[mf], fb_h[nf], acc_hh[mf][nf], 0, 0, 0);             \
                acc_x[mf][nf] = __builtin_amdgcn_mfma_f32_16x16x32_f16(       \
                    fa_h[mf], fb_l[nf], acc_x[mf][nf], 0, 0, 0);              \
                acc_x[mf][nf] = __builtin_amdgcn_mfma_f32_16x16x32_f16(       \
                    fa_l[mf], fb_h[nf], acc_x[mf][nf], 0, 0, 0);              \
            }                                                                 \
    }

    STAGE(0, 0);
    __syncthreads();                        // buf0 staged

    for (int t = 0; t < 32; t += 2) {
        if (t + 1 < 32) STAGE(1, (t + 1) * 32);
        COMPUTE(0);
        __syncthreads();                    // drains buf1 stage; buf0 reads done
        if (t + 2 < 32) STAGE(0, (t + 2) * 32);
        COMPUTE(1);
        __syncthreads();                    // drains buf0 stage; buf1 reads done
    }
#undef STAGE
#undef COMPUTE

    // epilogue: v = (hh + x/2048)/32 + bias, relu -> H
#pragma unroll
    for (int mf = 0; mf < 4; mf++) {
        const int row0 = rowBase + mw + mf * 16 + (lane >> 4) * 4;
#pragma unroll
        for (int nf = 0; nf < 4; nf++) {
            const int col = colBase + nw + nf * 16 + (lane & 15);
            const float b = bias_cat[col];
#pragma unroll
            for (int r = 0; r < 4; r++) {
                float v = (acc_hh[mf][nf][r] + acc_x[mf][nf][r] * (1.0f / S_LO))
                          * (1.0f / S_W) + b;
                H[(size_t)(row0 + r) * NTOT + col] = fmaxf(v, 0.f);
            }
        }
    }
}

// ---------------------------------------------------------------------------
// Per-token second layer on concat H [4096][2560]: importance, router logits,
// softmax, top-2. One block per token. (Scalar-strided reads — measured best.)
// ---------------------------------------------------------------------------
__global__ __launch_bounds__(256) void second_layer(
    const float* __restrict__ H,
    const float* __restrict__ wi2, const float* __restrict__ bi2,
    const float* __restrict__ wr2, const float* __restrict__ br2,
    const float* __restrict__ wu2, const float* __restrict__ bu2,
    float* __restrict__ oprobs, float* __restrict__ oimp,
    int* __restrict__ tke, float* __restrict__ tkp)
{
    const int t = blockIdx.x;
    const int tid = threadIdx.x;
    const float* hrow = H + (size_t)t * NTOT;

    float pi = 0.f;
    float pr[8], pu[8];
#pragma unroll
    for (int e = 0; e < 8; e++) { pr[e] = 0.f; pu[e] = 0.f; }

    for (int j = tid; j < HHALF; j += 256) pi = fmaf(hrow[j], wi2[j], pi);
    for (int j = tid; j < HDIM; j += 256) {
        float a = hrow[512 + j], b = hrow[1536 + j];
#pragma unroll
        for (int e = 0; e < 8; e++) {
            pr[e] = fmaf(a, wr2[j * 8 + e], pr[e]);
            pu[e] = fmaf(b, wu2[j * 8 + e], pu[e]);
        }
    }

#pragma unroll
    for (int off = 32; off > 0; off >>= 1) {
        pi += __shfl_down(pi, off, 64);
#pragma unroll
        for (int e = 0; e < 8; e++) {
            pr[e] += __shfl_down(pr[e], off, 64);
            pu[e] += __shfl_down(pu[e], off, 64);
        }
    }

    __shared__ float red[4][17];
    const int lane = tid & 63, wv = tid >> 6;
    if (lane == 0) {
        red[wv][0] = pi;
#pragma unroll
        for (int e = 0; e < 8; e++) { red[wv][1 + e] = pr[e]; red[wv][9 + e] = pu[e]; }
    }
    __syncthreads();

    if (tid == 0) {
        float si = red[0][0] + red[1][0] + red[2][0] + red[3][0] + bi2[0];
        float sig = 1.f / (1.f + expf(-si));
        oimp[t] = sig;
        const bool m = sig > 0.5f;
        float lg[8];
#pragma unroll
        for (int e = 0; e < 8; e++) {
            float vr = red[0][1 + e] + red[1][1 + e] + red[2][1 + e] + red[3][1 + e] + br2[e];
            float vu = red[0][9 + e] + red[1][9 + e] + red[2][9 + e] + red[3][9 + e] + bu2[e];
            lg[e] = m ? vr : vu;
        }
        float mx = lg[0];
#pragma unroll
        for (int e = 1; e < 8; e++) mx = fmaxf(mx, lg[e]);
        float p[8], sum = 0.f;
#pragma unroll
        for (int e = 0; e < 8; e++) { p[e] = expf(lg[e] - mx); sum += p[e]; }
        const float inv = 1.f / sum;
#pragma unroll
        for (int e = 0; e < 8; e++) { p[e] *= inv; oprobs[t * 8 + e] = p[e]; }
        int i1 = 0;
#pragma unroll
        for (int e = 1; e < 8; e++) if (p[e] > p[i1]) i1 = e;
        int i2 = (i1 == 0) ? 1 : 0;
#pragma unroll
        for (int e = 0; e < 8; e++) if (e != i1 && p[e] > p[i2]) i2 = e;
        const float ps = p[i1] + p[i2];
        tke[t]        = i1;
        tke[NTOK + t] = i2;
        tkp[t]        = p[i1] / ps;
        tkp[NTOK + t] = p[i2] / ps;
    }
}

// ---------------------------------------------------------------------------
// Fused scan+scatter+aux: single block. k-major capacity assignment, writes
// <=8192 nonzeros into the pre-zeroed output, and computes the aux loss.
// ---------------------------------------------------------------------------
__global__ __launch_bounds__(256) void scan_scatter_aux(
    const int* __restrict__ tke, const float* __restrict__ tkp,
    const float* __restrict__ oprobs, const float* __restrict__ oimp,
    float* __restrict__ out, float* __restrict__ oaux)
{
    __shared__ unsigned char se[2 * NTOK];
    __shared__ float         sp[2 * NTOK];
    __shared__ int  cnts[256][8];
    __shared__ float red[4][16];

    const int tid = threadIdx.x;
    const int lane = tid & 63, wv = tid >> 6;

    for (int i = tid; i < 2 * NTOK; i += 256) {
        se[i] = (unsigned char)tke[i];
        sp[i] = tkp[i];
    }

    // ---- aux accumulation (independent of LDS staging above)
    float ap[8], ai[8];
#pragma unroll
    for (int e = 0; e < 8; e++) { ap[e] = 0.f; ai[e] = 0.f; }
    for (int t = tid; t < NTOK; t += 256) {
        const float msk = (oimp[t] > 0.5f) ? 1.f : 0.f;
#pragma unroll
        for (int e = 0; e < 8; e++) {
            float p = oprobs[t * 8 + e];
            ap[e] += p;
            ai[e] = fmaf(msk, p, ai[e]);
        }
    }
#pragma unroll
    for (int off = 32; off > 0; off >>= 1) {
#pragma unroll
        for (int e = 0; e < 8; e++) {
            ap[e] += __shfl_down(ap[e], off, 64);
            ai[e] += __shfl_down(ai[e], off, 64);
        }
    }
    if (lane == 0) {
#pragma unroll
        for (int e = 0; e < 8; e++) { red[wv][e] = ap[e]; red[wv][8 + e] = ai[e]; }
    }
    __syncthreads();
    if (tid == 0) {
        float ent = 0.f, tot = 0.f, isv[8];
#pragma unroll
        for (int e = 0; e < 8; e++) {
            float spr = red[0][e] + red[1][e] + red[2][e] + red[3][e];
            float sm  = red[0][8 + e] + red[1][8 + e] + red[2][8 + e] + red[3][8 + e];
            float r = spr / (float)NTOK;
            ent += r * logf(r * 8.f + 1e-9f);
            isv[e] = sm + 1e-9f;
            tot += isv[e];
        }
        float ie = 0.f;
#pragma unroll
        for (int e = 0; e < 8; e++) {
            float q = isv[e] / tot;
            ie -= q * logf(q + 1e-9f);
        }
        oaux[0] = ent - 0.1f * (ie / logf(8.f));
    }

    // ---- scan + scatter
    const int base = tid * 32;
    int c[8];
#pragma unroll
    for (int e = 0; e < 8; e++) c[e] = 0;
    for (int i = 0; i < 32; i++) {
        int e = se[base + i];
#pragma unroll
        for (int k = 0; k < 8; k++) c[k] += (e == k) ? 1 : 0;
    }
#pragma unroll
    for (int e = 0; e < 8; e++) cnts[tid][e] = c[e];
    __syncthreads();

    if (tid < 8) {
        int run = 0;
        for (int i = 0; i < 256; i++) {
            int v = cnts[i][tid];
            cnts[i][tid] = run;
            run += v;
        }
    }
    __syncthreads();

    int basecnt[8];
#pragma unroll
    for (int e = 0; e < 8; e++) basecnt[e] = cnts[tid][e];

    float* comb = out + (size_t)NTOK * NEXP * CAP;

    for (int i = 0; i < 32; i++) {
        const int idx = base + i;
        const int e = se[idx];
        int pos = 0;
#pragma unroll
        for (int k = 0; k < 8; k++)
            if (e == k) { pos = basecnt[k]; basecnt[k]++; }
        if (pos < CAP) {
            const int tok = idx & (NTOK - 1);
            const size_t o = ((size_t)tok * NEXP + e) * CAP + pos;
            out[o]  = 1.0f;
            comb[o] = sp[idx];
        }
    }
}

// ---------------------------------------------------------------------------
// Fallback path kernels (only used if ws is unexpectedly small)
// ---------------------------------------------------------------------------
__global__ __launch_bounds__(256) void gemm_bias_relu(
    const float* __restrict__ A, const float* __restrict__ B,
    const float* __restrict__ bias, float* __restrict__ Hout, int N)
{
    __shared__ float As[16][132];
    __shared__ float Bs[16][132];
    const int tid = threadIdx.x;
    const int tx = tid & 15, ty = tid >> 4;
    const int rowBase = blockIdx.y * 128, colBase = blockIdx.x * 128;
    const int lrow = tid >> 1, lkq = (tid & 1) * 8;
    const int bkk = tid >> 4, bcol = (tid & 15) * 8;
    float acc[8][8];
#pragma unroll
    for (int i = 0; i < 8; i++)
#pragma unroll
        for (int j = 0; j < 8; j++) acc[i][j] = 0.f;
    const float* Aptr = A + (size_t)(rowBase + lrow) * HDIM + lkq;
    const float* Bptr = B + (size_t)bkk * N + colBase + bcol;
    for (int k0 = 0; k0 < HDIM; k0 += 16) {
        float4 a0 = *(const float4*)(Aptr + k0);
        float4 a1 = *(const float4*)(Aptr + k0 + 4);
        float4 b0 = *(const float4*)(Bptr + (size_t)k0 * N);
        float4 b1 = *(const float4*)(Bptr + (size_t)k0 * N + 4);
        __syncthreads();
        As[lkq + 0][lrow] = a0.x; As[lkq + 1][lrow] = a0.y;
        As[lkq + 2][lrow] = a0.z; As[lkq + 3][lrow] = a0.w;
        As[lkq + 4][lrow] = a1.x; As[lkq + 5][lrow] = a1.y;
        As[lkq + 6][lrow] = a1.z; As[lkq + 7][lrow] = a1.w;
        *(float4*)&Bs[bkk][bcol] = b0;
        *(float4*)&Bs[bkk][bcol + 4] = b1;
        __syncthreads();
#pragma unroll
        for (int kk = 0; kk < 16; kk++) {
            float4 x0 = *(const float4*)&As[kk][ty * 8];
            float4 x1 = *(const float4*)&As[kk][ty * 8 + 4];
            float4 y0 = *(const float4*)&Bs[kk][tx * 8];
            float4 y1 = *(const float4*)&Bs[kk][tx * 8 + 4];
            float av[8] = {x0.x, x0.y, x0.z, x0.w, x1.x, x1.y, x1.z, x1.w};
            float bv[8] = {y0.x, y0.y, y0.z, y0.w, y1.x, y1.y, y1.z, y1.w};
#pragma unroll
            for (int i = 0; i < 8; i++)
#pragma unroll
                for (int j = 0; j < 8; j++)
                    acc[i][j] = fmaf(av[i], bv[j], acc[i][j]);
        }
    }
#pragma unroll
    for (int i = 0; i < 8; i++) {
        const int r = rowBase + ty * 8 + i, c = colBase + tx * 8;
#pragma unroll
        for (int j = 0; j < 8; j += 4) {
            float4 v;
            v.x = fmaxf(acc[i][j + 0] + bias[c + j + 0], 0.f);
            v.y = fmaxf(acc[i][j + 1] + bias[c + j + 1], 0.f);
            v.z = fmaxf(acc[i][j + 2] + bias[c + j + 2], 0.f);
            v.w = fmaxf(acc[i][j + 3] + bias[c + j + 3], 0.f);
            *(float4*)&Hout[(size_t)r * N + c + j] = v;
        }
    }
}

__global__ __launch_bounds__(256) void zerofill_fb(float* __restrict__ out)
{
    f32x4* o4 = (f32x4*)out;
    const unsigned total4 = TOTAL_DC / 4;
    unsigned i = blockIdx.x * 256u + threadIdx.x;
    const unsigned stride = gridDim.x * 256u;
    const f32x4 z = {0.f, 0.f, 0.f, 0.f};
    for (; i < total4; i += stride) o4[i] = z;
}

__global__ __launch_bounds__(256) void second_layer_sep(
    const float* __restrict__ h_i, const float* __restrict__ h_r,
    const float* __restrict__ h_u,
    const float* __restrict__ wi2, const float* __restrict__ bi2,
    const float* __restrict__ wr2, const float* __restrict__ br2,
    const float* __restrict__ wu2, const float* __restrict__ bu2,
    float* __restrict__ oprobs, float* __restrict__ oimp,
    int* __restrict__ tke, float* __restrict__ tkp)
{
    const int t = blockIdx.x;
    const int tid = threadIdx.x;
    float pi = 0.f;
    float pr[8], pu[8];
#pragma unroll
    for (int e = 0; e < 8; e++) { pr[e] = 0.f; pu[e] = 0.f; }
    const float* hi = h_i + (size_t)t * HHALF;
    const float* hr = h_r + (size_t)t * HDIM;
    const float* hu = h_u + (size_t)t * HDIM;
    for (int j = tid; j < HHALF; j += 256) pi = fmaf(hi[j], wi2[j], pi);
    for (int j = tid; j < HDIM; j += 256) {
        float a = hr[j], b = hu[j];
#pragma unroll
        for (int e = 0; e < 8; e++) {
            pr[e] = fmaf(a, wr2[j * 8 + e], pr[e]);
            pu[e] = fmaf(b, wu2[j * 8 + e], pu[e]);
        }
    }
#pragma unroll
    for (int off = 32; off > 0; off >>= 1) {
        pi += __shfl_down(pi, off, 64);
#pragma unroll
        for (int e = 0; e < 8; e++) {
            pr[e] += __shfl_down(pr[e], off, 64);
            pu[e] += __shfl_down(pu[e], off, 64);
        }
    }
    __shared__ float red[4][17];
    const int lane = tid & 63, wv = tid >> 6;
    if (lane == 0) {
        red[wv][0] = pi;
#pragma unroll
        for (int e = 0; e < 8; e++) { red[wv][1 + e] = pr[e]; red[wv][9 + e] = pu[e]; }
    }
    __syncthreads();
    if (tid == 0) {
        float si = red[0][0] + red[1][0] + red[2][0] + red[3][0] + bi2[0];
        float sig = 1.f / (1.f + expf(-si));
        oimp[t] = sig;
        const bool m = sig > 0.5f;
        float lg[8];
#pragma unroll
        for (int e = 0; e < 8; e++) {
            float vr = red[0][1 + e] + red[1][1 + e] + red[2][1 + e] + red[3][1 + e] + br2[e];
            float vu = red[0][9 + e] + red[1][9 + e] + red[2][9 + e] + red[3][9 + e] + bu2[e];
            lg[e] = m ? vr : vu;
        }
        float mx = lg[0];
#pragma unroll
        for (int e = 1; e < 8; e++) mx = fmaxf(mx, lg[e]);
        float p[8], s = 0.f;
#pragma unroll
        for (int e = 0; e < 8; e++) { p[e] = expf(lg[e] - mx); s += p[e]; }
        const float inv = 1.f / s;
#pragma unroll
        for (int e = 0; e < 8; e++) { p[e] *= inv; oprobs[t * 8 + e] = p[e]; }
        int i1 = 0;
#pragma unroll
        for (int e = 1; e < 8; e++) if (p[e] > p[i1]) i1 = e;
        int i2 = (i1 == 0) ? 1 : 0;
#pragma unroll
        for (int e = 0; e < 8; e++) if (e != i1 && p[e] > p[i2]) i2 = e;
        const float ps = p[i1] + p[i2];
        tke[t]        = i1;
        tke[NTOK + t] = i2;
        tkp[t]        = p[i1] / ps;
        tkp[NTOK + t] = p[i2] / ps;
    }
}

// ---------------------------------------------------------------------------
extern "C" void kernel_launch(void* const* d_in, const int* in_sizes, int n_in,
                              void* d_out, int out_size, void* d_ws, size_t ws_size,
                              hipStream_t stream) {
    const float* x   = (const float*)d_in[0];
    const float* wi1 = (const float*)d_in[1];
    const float* bi1 = (const float*)d_in[2];
    const float* wi2 = (const float*)d_in[3];
    const float* bi2 = (const float*)d_in[4];
    const float* wr1 = (const float*)d_in[5];
    const float* br1 = (const float*)d_in[6];
    const float* wr2 = (const float*)d_in[7];
    const float* br2 = (const float*)d_in[8];
    const float* wu1 = (const float*)d_in[9];
    const float* bu1 = (const float*)d_in[10];
    const float* wu2 = (const float*)d_in[11];
    const float* bu2 = (const float*)d_in[12];

    float* out    = (float*)d_out;
    float* oprobs = out + (size_t)TOTAL_DC;
    float* oaux   = oprobs + NTOK * NEXP;
    float* oimp   = oaux + 1;

    // ws layout: H f32[4096*2560] | Ah,Al f16[4096*1024] | Bth,Btl f16[2560*1024]
    //            | bias f32[2560] | tke i32[8192] | tkp f32[8192]
    const size_t szH  = (size_t)NTOK * NTOT * 4;
    const size_t szA  = (size_t)NTOK * HDIM * 2;
    const size_t szB  = (size_t)NTOT * HDIM * 2;
    const size_t need = szH + 2 * szA + 2 * szB + NTOT * 4
                      + 2 * NTOK * 4 + 2 * NTOK * 4 + 4096;
    dim3 blk(256);

    if (ws_size >= need) {
        char* p = (char*)d_ws;
        float*    H    = (float*)p;            p += szH;
        _Float16* Ah   = (_Float16*)p;         p += szA;
        _Float16* Al   = (_Float16*)p;         p += szA;
        _Float16* Bth  = (_Float16*)p;         p += szB;
        _Float16* Btl  = (_Float16*)p;         p += szB;
        float*    bias = (float*)p;            p += NTOT * 4;
        int*      tke  = (int*)p;              p += 2 * NTOK * 4;
        float*    tkp  = (float*)p;

        prep<<<2689, blk, 0, stream>>>(x, wi1, wr1, wu1, bi1, br1, bu1,
                                       Ah, Al, Bth, Btl, bias);
        gemm_fill<<<2048, blk, 0, stream>>>(
            Ah, Al, Bth, Btl, bias, H, out);
        second_layer<<<NTOK, blk, 0, stream>>>(H, wi2, bi2, wr2, br2, wu2, bu2,
                                               oprobs, oimp, tke, tkp);
        scan_scatter_aux<<<1, blk, 0, stream>>>(tke, tkp, oprobs, oimp, out, oaux);
    } else {
        // fallback: fp32 GEMMs with activations in the dispatch region,
        // then zerofill + fused scan/scatter/aux.
        float* h_i = out;                                 // wiped by zerofill
        float* h_r = h_i + (size_t)NTOK * HHALF;
        float* h_u = h_r + (size_t)NTOK * HDIM;
        int*   tke  = (int*)d_ws;
        float* tkp  = (float*)d_ws + 2 * NTOK;

        gemm_bias_relu<<<dim3(HHALF / 128, NTOK / 128), blk, 0, stream>>>(x, wi1, bi1, h_i, HHALF);
        gemm_bias_relu<<<dim3(HDIM / 128, NTOK / 128), blk, 0, stream>>>(x, wr1, br1, h_r, HDIM);
        gemm_bias_relu<<<dim3(HDIM / 128, NTOK / 128), blk, 0, stream>>>(x, wu1, bu1, h_u, HDIM);
        second_layer_sep<<<NTOK, blk, 0, stream>>>(h_i, h_r, h_u, wi2, bi2, wr2, br2,
                                                   wu2, bu2, oprobs, oimp, tke, tkp);
        zerofill_fb<<<2048, blk, 0, stream>>>(out);
        scan_scatter_aux<<<1, blk, 0, stream>>>(tke, tkp, oprobs, oimp, out, oaux);
    }
}

// Round 15
// 175.733 us; speedup vs baseline: 1.2069x; 1.0089x over previous
//
#include <hip/hip_runtime.h>
#include <math.h>

#define HDIM  1024
#define HHALF 512
#define NEXP  8
#define NTOK  4096
#define CAP   1536
#define NTOT  2560                          // 512 + 1024 + 1024 concat output width
#define TOTAL_DC (2u * NTOK * NEXP * CAP)   // 100,663,296 floats (dispatch+combine)

typedef _Float16 f16x8 __attribute__((ext_vector_type(8)));
typedef float    f32x4 __attribute__((ext_vector_type(4)));

#define FILL_BLOCKS 1408
#define S_LO 2048.0f                        // lo-part scale (2^11)
#define S_W  32.0f                          // weight pre-scale

// ---------------------------------------------------------------------------
// prep: [0,2048) x -> A_hi/A_lo fp16 ; [2048,2688) weights -> Bt_hi/Bt_lo
// (transposed concat [2560][1024], pre-scaled x32) ; [2688] bias concat.
// ---------------------------------------------------------------------------
__global__ __launch_bounds__(256) void prep(
    const float* __restrict__ x,
    const float* __restrict__ wi1, const float* __restrict__ wr1,
    const float* __restrict__ wu1,
    const float* __restrict__ bi1, const float* __restrict__ br1,
    const float* __restrict__ bu1,
    _Float16* __restrict__ Ah, _Float16* __restrict__ Al,
    _Float16* __restrict__ Bth, _Float16* __restrict__ Btl,
    float* __restrict__ bias_cat)
{
    __shared__ float tile[64][65];
    const int bid = blockIdx.x, tid = threadIdx.x;

    if (bid < 2048) {                       // ---- x conversion, 8 elems/thread
        const int i8 = bid * 256 + tid;     // 0 .. 524287
        const float4* x4 = (const float4*)x;
        float4 v0 = x4[i8 * 2];
        float4 v1 = x4[i8 * 2 + 1];
        float f[8] = {v0.x, v0.y, v0.z, v0.w, v1.x, v1.y, v1.z, v1.w};
        f16x8 hi, lo;
#pragma unroll
        for (int j = 0; j < 8; j++) {
            _Float16 h = (_Float16)f[j];
            hi[j] = h;
            lo[j] = (_Float16)((f[j] - (float)h) * S_LO);
        }
        *(f16x8*)&Ah[(size_t)i8 * 8] = hi;
        *(f16x8*)&Al[(size_t)i8 * 8] = lo;
        return;
    }
    if (bid < 2688) {                       // ---- weight transpose+convert
        int local; const float* src; int C, nof;
        int b = bid - 2048;
        if (b < 128)      { src = wi1; C = 512;  nof = 0;    local = b; }
        else if (b < 384) { src = wr1; C = 1024; nof = 512;  local = b - 128; }
        else              { src = wu1; C = 1024; nof = 1536; local = b - 384; }
        const int nti = local >> 4, kti = local & 15;
#pragma unroll
        for (int p = 0; p < 16; p++) {
            int e = p * 256 + tid;
            int kr = e >> 6, nc = e & 63;
            tile[kr][nc] = src[(size_t)(kti * 64 + kr) * C + nti * 64 + nc];
        }
        __syncthreads();
#pragma unroll
        for (int p = 0; p < 16; p++) {
            int e = p * 256 + tid;
            int nl = e >> 6, kk = e & 63;
            float w32 = tile[kk][nl] * S_W;
            _Float16 h = (_Float16)w32;
            _Float16 l = (_Float16)((w32 - (float)h) * S_LO);
            const size_t o = (size_t)(nof + nti * 64 + nl) * 1024 + kti * 64 + kk;
            Bth[o] = h;
            Btl[o] = l;
        }
        return;
    }
    // ---- bias concat
    for (int i = tid; i < NTOT; i += 256) {
        float v = (i < 512) ? bi1[i] : (i < 1536) ? br1[i - 512] : bu1[i - 1536];
        bias_cat[i] = v;
    }
}

// ---------------------------------------------------------------------------
// gemm_fill: 2048 blocks in 256 octets of 8 (sub = blockIdx&7 = XCD).
// Octet groups of 8: first 11 groups = 7 GEMM octets + 1 fill octet; group 11
// = 3 GEMM + 5 fill; groups 12..31 = all fill. -> first 512 blocks are
// 448 GEMM + 64 fill, so the 402 MB zerofill streams under the GEMM phase.
// GEMM: fp16-split MFMA, XCD-sliced tiles, H output.
// K-loop: 2-deep prefetch with counted s_waitcnt vmcnt(8) + raw s_barrier
// (never drains vmcnt to 0 in steady state -> loads stay in flight across
// barriers, hiding write-stream-inflated HBM latency).
// ---------------------------------------------------------------------------
__global__ __launch_bounds__(256, 2) void gemm_fill(
    const _Float16* __restrict__ Ah, const _Float16* __restrict__ Al,
    const _Float16* __restrict__ Bth, const _Float16* __restrict__ Btl,
    const float* __restrict__ bias_cat, float* __restrict__ H,
    float* __restrict__ out)
{
    const int o = blockIdx.x >> 3, sub = blockIdx.x & 7;
    const int k = o >> 3, j = o & 7;        // octet group, position
    int g = -1, fo = 0;
    if (k < 11)       { if (j < 7) g = k * 7 + j; else fo = k; }
    else if (k == 11) { if (j < 3) g = 77 + j;    else fo = 11 + (j - 3); }
    else              { fo = 16 + ((k - 12) << 3) + j; }

    if (g < 0) {                            // ---------- fill path
        f32x4* o4 = (f32x4*)out;
        const unsigned total4 = TOTAL_DC / 4;            // 25,165,824
        unsigned i = (unsigned)(fo * 8 + sub) * 256u + threadIdx.x;
        const unsigned stride = FILL_BLOCKS * 256u;
        const f32x4 z = {0.f, 0.f, 0.f, 0.f};
        for (; i < total4; i += stride)
            __builtin_nontemporal_store(z, o4 + i);
        return;
    }

    __shared__ _Float16 lds[2][4][128][32];   // dbuf x {Ah|Al|Bh|Bl}, 64 KB

    const int tid = threadIdx.x;
    const int lane = tid & 63, wid = tid >> 6;

    // XCD-sliced mapping: xcd = sub; each XCD owns a bm-slice of 4, iterates
    // bm fastest so B panels are burst-reused.
    const int bm  = sub * 4 + (g & 3);        // 0..31
    const int bn  = g >> 2;                   // 0..19
    const int rowBase = bm * 128, colBase = bn * 128;

    // each wave stages its own tile type
    const _Float16* gb =
        (wid == 0) ? Ah  + (size_t)rowBase * 1024 :
        (wid == 1) ? Al  + (size_t)rowBase * 1024 :
        (wid == 2) ? Bth + (size_t)colBase * 1024 :
                     Btl + (size_t)colBase * 1024;
    const int lrow = lane >> 2;             // 0..15 within 16-row group
    // pre-swizzled 16B chunk within the 64B row (bank-spread, neutral/safe)
    const int lkgs = (lane & 3) ^ ((lane >> 3) & 3);

    f32x4 acc_hh[4][4], acc_x[4][4];
    const f32x4 z4 = {0.f, 0.f, 0.f, 0.f};
#pragma unroll
    for (int i = 0; i < 4; i++)
#pragma unroll
        for (int j2 = 0; j2 < 4; j2++) { acc_hh[i][j2] = z4; acc_x[i][j2] = z4; }

    const int mw = (wid >> 1) * 64, nw = (wid & 1) * 64;
    const int fr = lane & 15, s = lane >> 4;
    const int rs = s ^ ((fr >> 1) & 3);     // swizzled read chunk

#define STAGE(buf, k0)                                                        \
    {                                                                         \
        _Pragma("unroll")                                                     \
        for (int i = 0; i < 8; i++) {                                         \
            const int r = i * 16 + lrow;                                      \
            __builtin_amdgcn_global_load_lds(                                 \
                (const void*)(gb + (size_t)r * 1024 + (k0) + lkgs * 8),       \
                (void*)&lds[buf][wid][i * 16][0], 16, 0, 0);                  \
        }                                                                     \
    }

#define COMPUTE(buf)                                                          \
    {                                                                         \
        f16x8 fa_h[4], fa_l[4], fb_h[4], fb_l[4];                             \
        _Pragma("unroll")                                                     \
        for (int mf = 0; mf < 4; mf++) {                                      \
            fa_h[mf] = *(const f16x8*)&lds[buf][0][mw + mf * 16 + fr][rs * 8];\
            fa_l[mf] = *(const f16x8*)&lds[buf][1][mw + mf * 16 + fr][rs * 8];\
        }                                                                     \
        _Pragma("unroll")                                                     \
        for (int nf = 0; nf < 4; nf++) {                                      \
            fb_h[nf] = *(const f16x8*)&lds[buf][2][nw + nf * 16 + fr][rs * 8];\
            fb_l[nf] = *(const f16x8*)&lds[buf][3][nw + nf * 16 + fr][rs * 8];\
        }                                                                     \
        _Pragma("unroll")                                                     \
        for (int mf = 0; mf < 4; mf++)                                        \
            _Pragma("unroll")                                                 \
            for (int nf = 0; nf < 4; nf++) {                                  \
                acc_hh[mf][nf] = __builtin_amdgcn_mfma_f32_16x16x32_f16(      \
                    fa_h[mf], fb_h[nf], acc_hh[mf][nf], 0, 0, 0);             \
                acc_x[mf][nf] = __builtin_amdgcn_mfma_f32_16x16x32_f16(       \
                    fa_h[mf], fb_l[nf], acc_x[mf][nf], 0, 0, 0);              \
                acc_x[mf][nf] = __builtin_amdgcn_mfma_f32_16x16x32_f16(       \
                    fa_l[mf], fb_h[nf], acc_x[mf][nf], 0, 0, 0);              \
            }                                                                 \
    }

#define VMCNT8 { asm volatile("s_waitcnt vmcnt(8)" ::: "memory");             \
                 __builtin_amdgcn_sched_barrier(0); }
#define VMCNT0 { asm volatile("s_waitcnt vmcnt(0)" ::: "memory");             \
                 __builtin_amdgcn_sched_barrier(0); }
#define SBAR   __builtin_amdgcn_s_barrier()

    // prologue: stage tiles 0 and 1; wait for tile 0 only (8 newest in flight)
    STAGE(0, 0);
    STAGE(1, 32);
    VMCNT8; SBAR;

    // steady state: 2 tiles in flight, vmcnt never drained to 0
    for (int t = 0; t < 30; t += 2) {
        COMPUTE(0);                         // tile t (buf0 ready)
        SBAR;                               // all waves done reading buf0
        STAGE(0, (t + 2) * 32);             // prefetch tile t+2
        VMCNT8; SBAR;                       // tile t+1 (buf1) ready
        COMPUTE(1);                         // tile t+1
        SBAR;                               // all waves done reading buf1
        STAGE(1, (t + 3) * 32);             // prefetch tile t+3
        VMCNT8; SBAR;                       // tile t+2 (buf0) ready
    }
    // epilogue: tiles 30, 31
    COMPUTE(0);
    SBAR;
    VMCNT0; SBAR;                           // tile 31 (buf1) ready
    COMPUTE(1);

#undef STAGE
#undef COMPUTE
#undef VMCNT8
#undef VMCNT0
#undef SBAR

    // epilogue: v = (hh + x/2048)/32 + bias, relu -> H
#pragma unroll
    for (int mf = 0; mf < 4; mf++) {
        const int row0 = rowBase + mw + mf * 16 + (lane >> 4) * 4;
#pragma unroll
        for (int nf = 0; nf < 4; nf++) {
            const int col = colBase + nw + nf * 16 + (lane & 15);
            const float b = bias_cat[col];
#pragma unroll
            for (int r = 0; r < 4; r++) {
                float v = (acc_hh[mf][nf][r] + acc_x[mf][nf][r] * (1.0f / S_LO))
                          * (1.0f / S_W) + b;
                H[(size_t)(row0 + r) * NTOT + col] = fmaxf(v, 0.f);
            }
        }
    }
}

// ---------------------------------------------------------------------------
// Per-token second layer on concat H [4096][2560]: importance, router logits,
// softmax, top-2. One block per token. (Scalar-strided reads — measured best.)
// ---------------------------------------------------------------------------
__global__ __launch_bounds__(256) void second_layer(
    const float* __restrict__ H,
    const float* __restrict__ wi2, const float* __restrict__ bi2,
    const float* __restrict__ wr2, const float* __restrict__ br2,
    const float* __restrict__ wu2, const float* __restrict__ bu2,
    float* __restrict__ oprobs, float* __restrict__ oimp,
    int* __restrict__ tke, float* __restrict__ tkp)
{
    const int t = blockIdx.x;
    const int tid = threadIdx.x;
    const float* hrow = H + (size_t)t * NTOT;

    float pi = 0.f;
    float pr[8], pu[8];
#pragma unroll
    for (int e = 0; e < 8; e++) { pr[e] = 0.f; pu[e] = 0.f; }

    for (int j = tid; j < HHALF; j += 256) pi = fmaf(hrow[j], wi2[j], pi);
    for (int j = tid; j < HDIM; j += 256) {
        float a = hrow[512 + j], b = hrow[1536 + j];
#pragma unroll
        for (int e = 0; e < 8; e++) {
            pr[e] = fmaf(a, wr2[j * 8 + e], pr[e]);
            pu[e] = fmaf(b, wu2[j * 8 + e], pu[e]);
        }
    }

#pragma unroll
    for (int off = 32; off > 0; off >>= 1) {
        pi += __shfl_down(pi, off, 64);
#pragma unroll
        for (int e = 0; e < 8; e++) {
            pr[e] += __shfl_down(pr[e], off, 64);
            pu[e] += __shfl_down(pu[e], off, 64);
        }
    }

    __shared__ float red[4][17];
    const int lane = tid & 63, wv = tid >> 6;
    if (lane == 0) {
        red[wv][0] = pi;
#pragma unroll
        for (int e = 0; e < 8; e++) { red[wv][1 + e] = pr[e]; red[wv][9 + e] = pu[e]; }
    }
    __syncthreads();

    if (tid == 0) {
        float si = red[0][0] + red[1][0] + red[2][0] + red[3][0] + bi2[0];
        float sig = 1.f / (1.f + expf(-si));
        oimp[t] = sig;
        const bool m = sig > 0.5f;
        float lg[8];
#pragma unroll
        for (int e = 0; e < 8; e++) {
            float vr = red[0][1 + e] + red[1][1 + e] + red[2][1 + e] + red[3][1 + e] + br2[e];
            float vu = red[0][9 + e] + red[1][9 + e] + red[2][9 + e] + red[3][9 + e] + bu2[e];
            lg[e] = m ? vr : vu;
        }
        float mx = lg[0];
#pragma unroll
        for (int e = 1; e < 8; e++) mx = fmaxf(mx, lg[e]);
        float p[8], sum = 0.f;
#pragma unroll
        for (int e = 0; e < 8; e++) { p[e] = expf(lg[e] - mx); sum += p[e]; }
        const float inv = 1.f / sum;
#pragma unroll
        for (int e = 0; e < 8; e++) { p[e] *= inv; oprobs[t * 8 + e] = p[e]; }
        int i1 = 0;
#pragma unroll
        for (int e = 1; e < 8; e++) if (p[e] > p[i1]) i1 = e;
        int i2 = (i1 == 0) ? 1 : 0;
#pragma unroll
        for (int e = 0; e < 8; e++) if (e != i1 && p[e] > p[i2]) i2 = e;
        const float ps = p[i1] + p[i2];
        tke[t]        = i1;
        tke[NTOK + t] = i2;
        tkp[t]        = p[i1] / ps;
        tkp[NTOK + t] = p[i2] / ps;
    }
}

// ---------------------------------------------------------------------------
// Fused scan+scatter+aux: single block. k-major capacity assignment, writes
// <=8192 nonzeros into the pre-zeroed output, and computes the aux loss.
// ---------------------------------------------------------------------------
__global__ __launch_bounds__(256) void scan_scatter_aux(
    const int* __restrict__ tke, const float* __restrict__ tkp,
    const float* __restrict__ oprobs, const float* __restrict__ oimp,
    float* __restrict__ out, float* __restrict__ oaux)
{
    __shared__ unsigned char se[2 * NTOK];
    __shared__ float         sp[2 * NTOK];
    __shared__ int  cnts[256][8];
    __shared__ float red[4][16];

    const int tid = threadIdx.x;
    const int lane = tid & 63, wv = tid >> 6;

    for (int i = tid; i < 2 * NTOK; i += 256) {
        se[i] = (unsigned char)tke[i];
        sp[i] = tkp[i];
    }

    // ---- aux accumulation (independent of LDS staging above)
    float ap[8], ai[8];
#pragma unroll
    for (int e = 0; e < 8; e++) { ap[e] = 0.f; ai[e] = 0.f; }
    for (int t = tid; t < NTOK; t += 256) {
        const float msk = (oimp[t] > 0.5f) ? 1.f : 0.f;
#pragma unroll
        for (int e = 0; e < 8; e++) {
            float p = oprobs[t * 8 + e];
            ap[e] += p;
            ai[e] = fmaf(msk, p, ai[e]);
        }
    }
#pragma unroll
    for (int off = 32; off > 0; off >>= 1) {
#pragma unroll
        for (int e = 0; e < 8; e++) {
            ap[e] += __shfl_down(ap[e], off, 64);
            ai[e] += __shfl_down(ai[e], off, 64);
        }
    }
    if (lane == 0) {
#pragma unroll
        for (int e = 0; e < 8; e++) { red[wv][e] = ap[e]; red[wv][8 + e] = ai[e]; }
    }
    __syncthreads();
    if (tid == 0) {
        float ent = 0.f, tot = 0.f, isv[8];
#pragma unroll
        for (int e = 0; e < 8; e++) {
            float spr = red[0][e] + red[1][e] + red[2][e] + red[3][e];
            float sm  = red[0][8 + e] + red[1][8 + e] + red[2][8 + e] + red[3][8 + e];
            float r = spr / (float)NTOK;
            ent += r * logf(r * 8.f + 1e-9f);
            isv[e] = sm + 1e-9f;
            tot += isv[e];
        }
        float ie = 0.f;
#pragma unroll
        for (int e = 0; e < 8; e++) {
            float q = isv[e] / tot;
            ie -= q * logf(q + 1e-9f);
        }
        oaux[0] = ent - 0.1f * (ie / logf(8.f));
    }

    // ---- scan + scatter
    const int base = tid * 32;
    int c[8];
#pragma unroll
    for (int e = 0; e < 8; e++) c[e] = 0;
    for (int i = 0; i < 32; i++) {
        int e = se[base + i];
#pragma unroll
        for (int k = 0; k < 8; k++) c[k] += (e == k) ? 1 : 0;
    }
#pragma unroll
    for (int e = 0; e < 8; e++) cnts[tid][e] = c[e];
    __syncthreads();

    if (tid < 8) {
        int run = 0;
        for (int i = 0; i < 256; i++) {
            int v = cnts[i][tid];
            cnts[i][tid] = run;
            run += v;
        }
    }
    __syncthreads();

    int basecnt[8];
#pragma unroll
    for (int e = 0; e < 8; e++) basecnt[e] = cnts[tid][e];

    float* comb = out + (size_t)NTOK * NEXP * CAP;

    for (int i = 0; i < 32; i++) {
        const int idx = base + i;
        const int e = se[idx];
        int pos = 0;
#pragma unroll
        for (int k = 0; k < 8; k++)
            if (e == k) { pos = basecnt[k]; basecnt[k]++; }
        if (pos < CAP) {
            const int tok = idx & (NTOK - 1);
            const size_t o = ((size_t)tok * NEXP + e) * CAP + pos;
            out[o]  = 1.0f;
            comb[o] = sp[idx];
        }
    }
}

// ---------------------------------------------------------------------------
// Fallback path kernels (only used if ws is unexpectedly small)
// ---------------------------------------------------------------------------
__global__ __launch_bounds__(256) void gemm_bias_relu(
    const float* __restrict__ A, const float* __restrict__ B,
    const float* __restrict__ bias, float* __restrict__ Hout, int N)
{
    __shared__ float As[16][132];
    __shared__ float Bs[16][132];
    const int tid = threadIdx.x;
    const int tx = tid & 15, ty = tid >> 4;
    const int rowBase = blockIdx.y * 128, colBase = blockIdx.x * 128;
    const int lrow = tid >> 1, lkq = (tid & 1) * 8;
    const int bkk = tid >> 4, bcol = (tid & 15) * 8;
    float acc[8][8];
#pragma unroll
    for (int i = 0; i < 8; i++)
#pragma unroll
        for (int j = 0; j < 8; j++) acc[i][j] = 0.f;
    const float* Aptr = A + (size_t)(rowBase + lrow) * HDIM + lkq;
    const float* Bptr = B + (size_t)bkk * N + colBase + bcol;
    for (int k0 = 0; k0 < HDIM; k0 += 16) {
        float4 a0 = *(const float4*)(Aptr + k0);
        float4 a1 = *(const float4*)(Aptr + k0 + 4);
        float4 b0 = *(const float4*)(Bptr + (size_t)k0 * N);
        float4 b1 = *(const float4*)(Bptr + (size_t)k0 * N + 4);
        __syncthreads();
        As[lkq + 0][lrow] = a0.x; As[lkq + 1][lrow] = a0.y;
        As[lkq + 2][lrow] = a0.z; As[lkq + 3][lrow] = a0.w;
        As[lkq + 4][lrow] = a1.x; As[lkq + 5][lrow] = a1.y;
        As[lkq + 6][lrow] = a1.z; As[lkq + 7][lrow] = a1.w;
        *(float4*)&Bs[bkk][bcol] = b0;
        *(float4*)&Bs[bkk][bcol + 4] = b1;
        __syncthreads();
#pragma unroll
        for (int kk = 0; kk < 16; kk++) {
            float4 x0 = *(const float4*)&As[kk][ty * 8];
            float4 x1 = *(const float4*)&As[kk][ty * 8 + 4];
            float4 y0 = *(const float4*)&Bs[kk][tx * 8];
            float4 y1 = *(const float4*)&Bs[kk][tx * 8 + 4];
            float av[8] = {x0.x, x0.y, x0.z, x0.w, x1.x, x1.y, x1.z, x1.w};
            float bv[8] = {y0.x, y0.y, y0.z, y0.w, y1.x, y1.y, y1.z, y1.w};
#pragma unroll
            for (int i = 0; i < 8; i++)
#pragma unroll
                for (int j = 0; j < 8; j++)
                    acc[i][j] = fmaf(av[i], bv[j], acc[i][j]);
        }
    }
#pragma unroll
    for (int i = 0; i < 8; i++) {
        const int r = rowBase + ty * 8 + i, c = colBase + tx * 8;
#pragma unroll
        for (int j = 0; j < 8; j += 4) {
            float4 v;
            v.x = fmaxf(acc[i][j + 0] + bias[c + j + 0], 0.f);
            v.y = fmaxf(acc[i][j + 1] + bias[c + j + 1], 0.f);
            v.z = fmaxf(acc[i][j + 2] + bias[c + j + 2], 0.f);
            v.w = fmaxf(acc[i][j + 3] + bias[c + j + 3], 0.f);
            *(float4*)&Hout[(size_t)r * N + c + j] = v;
        }
    }
}

__global__ __launch_bounds__(256) void zerofill_fb(float* __restrict__ out)
{
    f32x4* o4 = (f32x4*)out;
    const unsigned total4 = TOTAL_DC / 4;
    unsigned i = blockIdx.x * 256u + threadIdx.x;
    const unsigned stride = gridDim.x * 256u;
    const f32x4 z = {0.f, 0.f, 0.f, 0.f};
    for (; i < total4; i += stride) o4[i] = z;
}

__global__ __launch_bounds__(256) void second_layer_sep(
    const float* __restrict__ h_i, const float* __restrict__ h_r,
    const float* __restrict__ h_u,
    const float* __restrict__ wi2, const float* __restrict__ bi2,
    const float* __restrict__ wr2, const float* __restrict__ br2,
    const float* __restrict__ wu2, const float* __restrict__ bu2,
    float* __restrict__ oprobs, float* __restrict__ oimp,
    int* __restrict__ tke, float* __restrict__ tkp)
{
    const int t = blockIdx.x;
    const int tid = threadIdx.x;
    float pi = 0.f;
    float pr[8], pu[8];
#pragma unroll
    for (int e = 0; e < 8; e++) { pr[e] = 0.f; pu[e] = 0.f; }
    const float* hi = h_i + (size_t)t * HHALF;
    const float* hr = h_r + (size_t)t * HDIM;
    const float* hu = h_u + (size_t)t * HDIM;
    for (int j = tid; j < HHALF; j += 256) pi = fmaf(hi[j], wi2[j], pi);
    for (int j = tid; j < HDIM; j += 256) {
        float a = hr[j], b = hu[j];
#pragma unroll
        for (int e = 0; e < 8; e++) {
            pr[e] = fmaf(a, wr2[j * 8 + e], pr[e]);
            pu[e] = fmaf(b, wu2[j * 8 + e], pu[e]);
        }
    }
#pragma unroll
    for (int off = 32; off > 0; off >>= 1) {
        pi += __shfl_down(pi, off, 64);
#pragma unroll
        for (int e = 0; e < 8; e++) {
            pr[e] += __shfl_down(pr[e], off, 64);
            pu[e] += __shfl_down(pu[e], off, 64);
        }
    }
    __shared__ float red[4][17];
    const int lane = tid & 63, wv = tid >> 6;
    if (lane == 0) {
        red[wv][0] = pi;
#pragma unroll
        for (int e = 0; e < 8; e++) { red[wv][1 + e] = pr[e]; red[wv][9 + e] = pu[e]; }
    }
    __syncthreads();
    if (tid == 0) {
        float si = red[0][0] + red[1][0] + red[2][0] + red[3][0] + bi2[0];
        float sig = 1.f / (1.f + expf(-si));
        oimp[t] = sig;
        const bool m = sig > 0.5f;
        float lg[8];
#pragma unroll
        for (int e = 0; e < 8; e++) {
            float vr = red[0][1 + e] + red[1][1 + e] + red[2][1 + e] + red[3][1 + e] + br2[e];
            float vu = red[0][9 + e] + red[1][9 + e] + red[2][9 + e] + red[3][9 + e] + bu2[e];
            lg[e] = m ? vr : vu;
        }
        float mx = lg[0];
#pragma unroll
        for (int e = 1; e < 8; e++) mx = fmaxf(mx, lg[e]);
        float p[8], s = 0.f;
#pragma unroll
        for (int e = 0; e < 8; e++) { p[e] = expf(lg[e] - mx); s += p[e]; }
        const float inv = 1.f / s;
#pragma unroll
        for (int e = 0; e < 8; e++) { p[e] *= inv; oprobs[t * 8 + e] = p[e]; }
        int i1 = 0;
#pragma unroll
        for (int e = 1; e < 8; e++) if (p[e] > p[i1]) i1 = e;
        int i2 = (i1 == 0) ? 1 : 0;
#pragma unroll
        for (int e = 0; e < 8; e++) if (e != i1 && p[e] > p[i2]) i2 = e;
        const float ps = p[i1] + p[i2];
        tke[t]        = i1;
        tke[NTOK + t] = i2;
        tkp[t]        = p[i1] / ps;
        tkp[NTOK + t] = p[i2] / ps;
    }
}

// ---------------------------------------------------------------------------
extern "C" void kernel_launch(void* const* d_in, const int* in_sizes, int n_in,
                              void* d_out, int out_size, void* d_ws, size_t ws_size,
                              hipStream_t stream) {
    const float* x   = (const float*)d_in[0];
    const float* wi1 = (const float*)d_in[1];
    const float* bi1 = (const float*)d_in[2];
    const float* wi2 = (const float*)d_in[3];
    const float* bi2 = (const float*)d_in[4];
    const float* wr1 = (const float*)d_in[5];
    const float* br1 = (const float*)d_in[6];
    const float* wr2 = (const float*)d_in[7];
    const float* br2 = (const float*)d_in[8];
    const float* wu1 = (const float*)d_in[9];
    const float* bu1 = (const float*)d_in[10];
    const float* wu2 = (const float*)d_in[11];
    const float* bu2 = (const float*)d_in[12];

    float* out    = (float*)d_out;
    float* oprobs = out + (size_t)TOTAL_DC;
    float* oaux   = oprobs + NTOK * NEXP;
    float* oimp   = oaux + 1;

    // ws layout: H f32[4096*2560] | Ah,Al f16[4096*1024] | Bth,Btl f16[2560*1024]
    //            | bias f32[2560] | tke i32[8192] | tkp f32[8192]
    const size_t szH  = (size_t)NTOK * NTOT * 4;
    const size_t szA  = (size_t)NTOK * HDIM * 2;
    const size_t szB  = (size_t)NTOT * HDIM * 2;
    const size_t need = szH + 2 * szA + 2 * szB + NTOT * 4
                      + 2 * NTOK * 4 + 2 * NTOK * 4 + 4096;
    dim3 blk(256);

    if (ws_size >= need) {
        char* p = (char*)d_ws;
        float*    H    = (float*)p;            p += szH;
        _Float16* Ah   = (_Float16*)p;         p += szA;
        _Float16* Al   = (_Float16*)p;         p += szA;
        _Float16* Bth  = (_Float16*)p;         p += szB;
        _Float16* Btl  = (_Float16*)p;         p += szB;
        float*    bias = (float*)p;            p += NTOT * 4;
        int*      tke  = (int*)p;              p += 2 * NTOK * 4;
        float*    tkp  = (float*)p;

        prep<<<2689, blk, 0, stream>>>(x, wi1, wr1, wu1, bi1, br1, bu1,
                                       Ah, Al, Bth, Btl, bias);
        gemm_fill<<<2048, blk, 0, stream>>>(
            Ah, Al, Bth, Btl, bias, H, out);
        second_layer<<<NTOK, blk, 0, stream>>>(H, wi2, bi2, wr2, br2, wu2, bu2,
                                               oprobs, oimp, tke, tkp);
        scan_scatter_aux<<<1, blk, 0, stream>>>(tke, tkp, oprobs, oimp, out, oaux);
    } else {
        // fallback: fp32 GEMMs with activations in the dispatch region,
        // then zerofill + fused scan/scatter/aux.
        float* h_i = out;                                 // wiped by zerofill
        float* h_r = h_i + (size_t)NTOK * HHALF;
        float* h_u = h_r + (size_t)NTOK * HDIM;
        int*   tke  = (int*)d_ws;
        float* tkp  = (float*)d_ws + 2 * NTOK;

        gemm_bias_relu<<<dim3(HHALF / 128, NTOK / 128), blk, 0, stream>>>(x, wi1, bi1, h_i, HHALF);
        gemm_bias_relu<<<dim3(HDIM / 128, NTOK / 128), blk, 0, stream>>>(x, wr1, br1, h_r, HDIM);
        gemm_bias_relu<<<dim3(HDIM / 128, NTOK / 128), blk, 0, stream>>>(x, wu1, bu1, h_u, HDIM);
        second_layer_sep<<<NTOK, blk, 0, stream>>>(h_i, h_r, h_u, wi2, bi2, wr2, br2,
                                                   wu2, bu2, oprobs, oimp, tke, tkp);
        zerofill_fb<<<2048, blk, 0, stream>>>(out);
        scan_scatter_aux<<<1, blk, 0, stream>>>(tke, tkp, oprobs, oimp, out, oaux);
    }
}